// Round 5
// baseline (1663.219 us; speedup 1.0000x reference)
//
#include <hip/hip_runtime.h>
#include <hip/hip_bf16.h>

#define GN 100000
#define GE 600000
#define SCAN_NBLK 98   // ceil(GN / 1024)

typedef __bf16 bf16x8 __attribute__((ext_vector_type(8)));
typedef __bf16 bf16x4 __attribute__((ext_vector_type(4)));
typedef float  f32x4  __attribute__((ext_vector_type(4)));

// ---------------------------------------------------------------------------
// Weight pre-conversion: fp32 -> (hi, lo) bf16 planes, done ONCE per launch.
// [0,16384) = W_in[128,128]; [16384,65536) = W_convs[3][128][128];
// [65536,98304) = W_out[64,512]. All row-major [OC, K].
// ---------------------------------------------------------------------------
__global__ __launch_bounds__(256) void convert_w(
    const float* __restrict__ Win, const float* __restrict__ Wc,
    const float* __restrict__ Wout,
    __bf16* __restrict__ hi, __bf16* __restrict__ lo)
{
    const int i = blockIdx.x * 256 + threadIdx.x;
    if (i >= 98304) return;
    float v;
    if (i < 16384)      v = Win[i];
    else if (i < 65536) v = Wc[i - 16384];
    else                v = Wout[i - 65536];
    const __bf16 h = (__bf16)v;
    hi[i] = h;
    lo[i] = (__bf16)(v - (float)h);
}

// ---------------------------------------------------------------------------
// Fused GIN layer: C[64-row tile, 128] = (gather(H) if GATHER else H) @ W^T + b
// Phase A (GATHER): edge-parallel. Acc[64][128] fp32 in LDS initialized with
//   self rows; all (edge x float) items of the block's contiguous CSR slice
//   distributed over 512 threads -> independent global loads + ds_add_f32.
//   (Replaces wave-per-row serial chains: latency-bound -> throughput-bound.)
// Phase B: 3-term split MFMA (hi*hi + hi*lo + lo*hi), K=128, W pre-converted.
// Phase C: acc -> LDS fp32 -> full-row 512B coalesced float4 stores.
// Block 512 = 8 waves; wave tile 32x32; BM=64, BN=128.
// ---------------------------------------------------------------------------
template<bool GATHER>
__global__ __launch_bounds__(512, 2) void gin_layer(
    const float* __restrict__ H, int ldH,
    const int* __restrict__ row_start,   // [GN] CSR row offsets (by dst)
    const int2* __restrict__ csr2,       // [GE] (src, dst), sorted by dst
    const __bf16* __restrict__ Whi,      // [128,128]
    const __bf16* __restrict__ Wlo,
    const float* __restrict__ bias,      // [128]
    float* __restrict__ C, int ldC)
{
    constexpr int K   = 128;
    constexpr int ALD = 136;   // bf16 LDS ld: 128 + 8 (16B-aligned rows)
    constexpr int CLD = 132;   // fp32 epilogue ld: 128 + 4
    constexpr int SMEM = GATHER ? (32768 + 34816) : 34816;

    __shared__ char smem_raw[SMEM];
    float*  Acc = (float*)smem_raw;                              // gather accumulator
    __bf16* Ahi = (__bf16*)(smem_raw + (GATHER ? 32768 : 0));
    __bf16* Alo = Ahi + 64 * ALD;
    float*  Cst = (float*)smem_raw;                              // epilogue (reuse)

    const int tid  = threadIdx.x;
    const int wave = tid >> 6;
    const int lane = tid & 63;
    const int row0 = blockIdx.x * 64;
    const int wm   = (wave >> 2) * 32;   // 0/32
    const int wn   = (wave & 3) * 32;    // 0/32/64/96
    const int quad = lane >> 4;
    const int l15  = lane & 15;

    // ---- Phase A: build A-tile (hi/lo bf16) in LDS ----
    if (GATHER) {
        // A1: init Acc with self rows (coalesced)
#pragma unroll
        for (int p = 0; p < 4; ++p) {
            const int q  = tid + p * 512;     // float4 index, [0,2048)
            const int r  = q >> 5;            // 32 float4 per row
            const int c4 = (q & 31) * 4;
            float4 v = make_float4(0.f, 0.f, 0.f, 0.f);
            if (row0 + r < GN) v = *(const float4*)(H + (size_t)(row0 + r) * ldH + c4);
            *(float4*)&Acc[r * 128 + c4] = v;
        }
        __syncthreads();

        // A2: edge-parallel accumulate. Items = (edges in block) x 128 floats.
        const int e0 = row_start[row0];
        const int e1 = (row0 + 64 >= GN) ? GE : row_start[row0 + 64];
        const int n_items = (e1 - e0) * 128;

        int it = tid;
        for (; it + 3 * 512 < n_items; it += 4 * 512) {
            const int i0 = it, i1 = it + 512, i2 = it + 1024, i3 = it + 1536;
            const int2 s0 = csr2[e0 + (i0 >> 7)];
            const int2 s1 = csr2[e0 + (i1 >> 7)];
            const int2 s2 = csr2[e0 + (i2 >> 7)];
            const int2 s3 = csr2[e0 + (i3 >> 7)];
            const float v0 = H[(size_t)s0.x * ldH + (i0 & 127)];
            const float v1 = H[(size_t)s1.x * ldH + (i1 & 127)];
            const float v2 = H[(size_t)s2.x * ldH + (i2 & 127)];
            const float v3 = H[(size_t)s3.x * ldH + (i3 & 127)];
            atomicAdd(&Acc[(s0.y - row0) * 128 + (i0 & 127)], v0);
            atomicAdd(&Acc[(s1.y - row0) * 128 + (i1 & 127)], v1);
            atomicAdd(&Acc[(s2.y - row0) * 128 + (i2 & 127)], v2);
            atomicAdd(&Acc[(s3.y - row0) * 128 + (i3 & 127)], v3);
        }
        for (; it < n_items; it += 512) {
            const int2 sd = csr2[e0 + (it >> 7)];
            const float v = H[(size_t)sd.x * ldH + (it & 127)];
            atomicAdd(&Acc[(sd.y - row0) * 128 + (it & 127)], v);
        }
        __syncthreads();

        // A3: convert Acc fp32 -> hi/lo bf16 tiles
#pragma unroll
        for (int p = 0; p < 4; ++p) {
            const int q  = tid + p * 512;
            const int r  = q >> 5;
            const int c4 = (q & 31) * 4;
            const float4 v4 = *(const float4*)&Acc[r * 128 + c4];
            const __bf16 h0 = (__bf16)v4.x, h1 = (__bf16)v4.y,
                         h2 = (__bf16)v4.z, h3 = (__bf16)v4.w;
            const int idx = r * ALD + c4;
            *(bf16x4*)&Ahi[idx] = (bf16x4){h0, h1, h2, h3};
            *(bf16x4*)&Alo[idx] = (bf16x4){(__bf16)(v4.x - (float)h0),
                                           (__bf16)(v4.y - (float)h1),
                                           (__bf16)(v4.z - (float)h2),
                                           (__bf16)(v4.w - (float)h3)};
        }
    } else {
#pragma unroll
        for (int p = 0; p < 4; ++p) {
            const int q  = tid + p * 512;
            const int f  = q * 4;
            const int r  = f >> 7;       // 128 floats per row
            const int kc = f & 127;
            float4 v4 = make_float4(0.f, 0.f, 0.f, 0.f);
            const int gr = row0 + r;
            if (gr < GN) v4 = *(const float4*)(H + (size_t)gr * ldH + kc);
            const __bf16 h0 = (__bf16)v4.x, h1 = (__bf16)v4.y,
                         h2 = (__bf16)v4.z, h3 = (__bf16)v4.w;
            const int idx = r * ALD + kc;
            *(bf16x4*)&Ahi[idx] = (bf16x4){h0, h1, h2, h3};
            *(bf16x4*)&Alo[idx] = (bf16x4){(__bf16)(v4.x - (float)h0),
                                           (__bf16)(v4.y - (float)h1),
                                           (__bf16)(v4.z - (float)h2),
                                           (__bf16)(v4.w - (float)h3)};
        }
    }
    __syncthreads();

    // ---- Phase B: MFMA ----
    f32x4 acc[2][2];
#pragma unroll
    for (int i = 0; i < 2; ++i)
#pragma unroll
        for (int j = 0; j < 2; ++j) acc[i][j] = (f32x4)(0.0f);

#pragma unroll
    for (int ks = 0; ks < 4; ++ks) {
        const int kt = ks * 32 + quad * 8;
        bf16x8 ahi[2], alo[2];
#pragma unroll
        for (int mt = 0; mt < 2; ++mt) {
            const int idx = (wm + mt * 16 + l15) * ALD + kt;
            ahi[mt] = *(const bf16x8*)&Ahi[idx];
            alo[mt] = *(const bf16x8*)&Alo[idx];
        }
        bf16x8 whi[2], wlo[2];
#pragma unroll
        for (int nt = 0; nt < 2; ++nt) {
            const int n = wn + nt * 16 + l15;
            whi[nt] = *(const bf16x8*)(Whi + (size_t)n * K + kt);
            wlo[nt] = *(const bf16x8*)(Wlo + (size_t)n * K + kt);
        }
#pragma unroll
        for (int mt = 0; mt < 2; ++mt)
#pragma unroll
            for (int nt = 0; nt < 2; ++nt) {
                acc[mt][nt] = __builtin_amdgcn_mfma_f32_16x16x32_bf16(
                    ahi[mt], whi[nt], acc[mt][nt], 0, 0, 0);
                acc[mt][nt] = __builtin_amdgcn_mfma_f32_16x16x32_bf16(
                    ahi[mt], wlo[nt], acc[mt][nt], 0, 0, 0);
                acc[mt][nt] = __builtin_amdgcn_mfma_f32_16x16x32_bf16(
                    alo[mt], whi[nt], acc[mt][nt], 0, 0, 0);
            }
    }
    __syncthreads();

    // ---- Phase C: epilogue via LDS, full-row coalesced stores ----
#pragma unroll
    for (int nt = 0; nt < 2; ++nt) {
        const int col = wn + nt * 16 + l15;
        const float b = bias[col];
#pragma unroll
        for (int mt = 0; mt < 2; ++mt)
#pragma unroll
            for (int r4 = 0; r4 < 4; ++r4)
                Cst[(wm + mt * 16 + quad * 4 + r4) * CLD + col] = acc[mt][nt][r4] + b;
    }
    __syncthreads();
#pragma unroll
    for (int p = 0; p < 4; ++p) {
        const int q  = tid + p * 512;
        const int r  = q >> 5;           // 32 float4 per row
        const int c4 = (q & 31) * 4;
        const int gr = row0 + r;
        if (gr < GN)
            *(float4*)(C + (size_t)gr * ldC + c4) = *(const float4*)&Cst[r * CLD + c4];
    }
}

// ---------------------------------------------------------------------------
// Final projection + fused softmax: out[GN,64] = softmax(cat @ W_out^T + b)
// BM=128, BN=64 (full row per block), K=512 in BK=64 chunks.
// ---------------------------------------------------------------------------
__global__ __launch_bounds__(512, 2) void final_gemm_softmax(
    const float* __restrict__ A,        // cat, ld 512
    const __bf16* __restrict__ Whi,     // [64,512]
    const __bf16* __restrict__ Wlo,
    const float* __restrict__ bias,     // [64]
    float* __restrict__ out)            // [GN,64]
{
    constexpr int K   = 512;
    constexpr int ALD = 72;    // 64 + 8
    constexpr int CLD = 68;    // 64 + 4

    __shared__ char smem_raw[128 * ALD * 2 * 2];   // 36864 B
    __bf16* Ahi = (__bf16*)smem_raw;
    __bf16* Alo = Ahi + 128 * ALD;
    float*  Cst = (float*)smem_raw;                // 128*68*4 = 34816 B

    const int tid  = threadIdx.x;
    const int wave = tid >> 6;
    const int lane = tid & 63;
    const int row0 = blockIdx.x * 128;
    const int wm   = (wave >> 1) * 32;   // 0/32/64/96
    const int wn   = (wave & 1) * 32;    // 0/32
    const int quad = lane >> 4;
    const int l15  = lane & 15;

    f32x4 acc[2][2];
#pragma unroll
    for (int i = 0; i < 2; ++i)
#pragma unroll
        for (int j = 0; j < 2; ++j) acc[i][j] = (f32x4)(0.0f);

    for (int k0 = 0; k0 < K; k0 += 64) {
#pragma unroll
        for (int p = 0; p < 4; ++p) {
            const int q  = tid + p * 512;
            const int f  = q * 4;
            const int r  = f >> 6;       // 64 floats per row-chunk
            const int kc = f & 63;
            float4 v4 = make_float4(0.f, 0.f, 0.f, 0.f);
            const int gr = row0 + r;
            if (gr < GN) v4 = *(const float4*)(A + (size_t)gr * 512 + k0 + kc);
            const __bf16 h0 = (__bf16)v4.x, h1 = (__bf16)v4.y,
                         h2 = (__bf16)v4.z, h3 = (__bf16)v4.w;
            const int idx = r * ALD + kc;
            *(bf16x4*)&Ahi[idx] = (bf16x4){h0, h1, h2, h3};
            *(bf16x4*)&Alo[idx] = (bf16x4){(__bf16)(v4.x - (float)h0),
                                           (__bf16)(v4.y - (float)h1),
                                           (__bf16)(v4.z - (float)h2),
                                           (__bf16)(v4.w - (float)h3)};
        }
        __syncthreads();

#pragma unroll
        for (int ks = 0; ks < 2; ++ks) {
            const int kt = ks * 32 + quad * 8;
            bf16x8 ahi[2], alo[2];
#pragma unroll
            for (int mt = 0; mt < 2; ++mt) {
                const int idx = (wm + mt * 16 + l15) * ALD + kt;
                ahi[mt] = *(const bf16x8*)&Ahi[idx];
                alo[mt] = *(const bf16x8*)&Alo[idx];
            }
            bf16x8 whi[2], wlo[2];
#pragma unroll
            for (int nt = 0; nt < 2; ++nt) {
                const int n = wn + nt * 16 + l15;
                whi[nt] = *(const bf16x8*)(Whi + (size_t)n * K + k0 + kt);
                wlo[nt] = *(const bf16x8*)(Wlo + (size_t)n * K + k0 + kt);
            }
#pragma unroll
            for (int mt = 0; mt < 2; ++mt)
#pragma unroll
                for (int nt = 0; nt < 2; ++nt) {
                    acc[mt][nt] = __builtin_amdgcn_mfma_f32_16x16x32_bf16(
                        ahi[mt], whi[nt], acc[mt][nt], 0, 0, 0);
                    acc[mt][nt] = __builtin_amdgcn_mfma_f32_16x16x32_bf16(
                        ahi[mt], wlo[nt], acc[mt][nt], 0, 0, 0);
                    acc[mt][nt] = __builtin_amdgcn_mfma_f32_16x16x32_bf16(
                        alo[mt], whi[nt], acc[mt][nt], 0, 0, 0);
                }
        }
        __syncthreads();
    }

    // epilogue -> LDS, + bias
#pragma unroll
    for (int nt = 0; nt < 2; ++nt) {
        const int col = wn + nt * 16 + l15;
        const float b = bias[col];
#pragma unroll
        for (int mt = 0; mt < 2; ++mt)
#pragma unroll
            for (int r4 = 0; r4 < 4; ++r4)
                Cst[(wm + mt * 16 + quad * 4 + r4) * CLD + col] = acc[mt][nt][r4] + b;
    }
    __syncthreads();

    // fused softmax: 8 waves x 16 rows, one wave per row, 64 lanes = 64 cols
    for (int i = 0; i < 16; ++i) {
        const int r = wave * 16 + i;
        const float v = Cst[r * CLD + lane];
        float m = v;
#pragma unroll
        for (int off = 32; off > 0; off >>= 1) m = fmaxf(m, __shfl_xor(m, off));
        const float e = __expf(v - m);
        float s = e;
#pragma unroll
        for (int off = 32; off > 0; off >>= 1) s += __shfl_xor(s, off);
        const int gr = row0 + r;
        if (gr < GN) out[(size_t)gr * 64 + lane] = e / s;
    }
}

// ---------------------------------------------------------------------------
// CSR construction (graph static; built once per launch, used 3x)
// ---------------------------------------------------------------------------
__global__ __launch_bounds__(256) void count_deg(const int* __restrict__ dst,
                                                 int* __restrict__ deg)
{
    const int e = blockIdx.x * 256 + threadIdx.x;
    if (e < GE) atomicAdd(&deg[dst[e]], 1);
}

__global__ __launch_bounds__(256) void scan_pass1(const int* __restrict__ deg,
                                                  int* __restrict__ excl,
                                                  int* __restrict__ blockSums)
{
    __shared__ int s[256];
    const int t = threadIdx.x;
    const int base = blockIdx.x * 1024 + t * 4;

    int4 v = make_int4(0, 0, 0, 0);
    if (base + 3 < GN) {
        v = *(const int4*)(deg + base);
    } else {
        if (base + 0 < GN) v.x = deg[base + 0];
        if (base + 1 < GN) v.y = deg[base + 1];
        if (base + 2 < GN) v.z = deg[base + 2];
        if (base + 3 < GN) v.w = deg[base + 3];
    }
    const int mysum = v.x + v.y + v.z + v.w;
    s[t] = mysum;
    __syncthreads();
    for (int off = 1; off < 256; off <<= 1) {
        const int val = (t >= off) ? s[t - off] : 0;
        __syncthreads();
        s[t] += val;
        __syncthreads();
    }
    int4 o;
    o.x = s[t] - mysum;
    o.y = o.x + v.x;
    o.z = o.y + v.y;
    o.w = o.z + v.z;
    if (base + 3 < GN) {
        *(int4*)(excl + base) = o;
    } else {
        if (base + 0 < GN) excl[base + 0] = o.x;
        if (base + 1 < GN) excl[base + 1] = o.y;
        if (base + 2 < GN) excl[base + 2] = o.z;
        if (base + 3 < GN) excl[base + 3] = o.w;
    }
    if (t == 255) blockSums[blockIdx.x] = s[255];
}

__global__ __launch_bounds__(128) void scan_pass2(const int* __restrict__ blockSums,
                                                  int* __restrict__ blockOffs, int n)
{
    __shared__ int s[128];
    const int t = threadIdx.x;
    const int v = (t < n) ? blockSums[t] : 0;
    s[t] = v;
    __syncthreads();
    for (int off = 1; off < 128; off <<= 1) {
        const int val = (t >= off) ? s[t - off] : 0;
        __syncthreads();
        s[t] += val;
        __syncthreads();
    }
    if (t < n) blockOffs[t] = s[t] - v;
}

__global__ __launch_bounds__(256) void scan_pass3(int* __restrict__ excl,
                                                  const int* __restrict__ blockOffs,
                                                  int* __restrict__ cursor)
{
    const int i = blockIdx.x * 256 + threadIdx.x;
    if (i >= GN) return;
    const int v = excl[i] + blockOffs[i >> 10];
    excl[i]   = v;   // row_start
    cursor[i] = v;   // running cursor for fill
}

__global__ __launch_bounds__(256) void fill_csr(const int* __restrict__ src,
                                                const int* __restrict__ dst,
                                                int* __restrict__ cursor,
                                                int2* __restrict__ csr2)
{
    const int e = blockIdx.x * 256 + threadIdx.x;
    if (e >= GE) return;
    const int d = dst[e];
    const int pos = atomicAdd(&cursor[d], 1);
    csr2[pos] = make_int2(src[e], d);
}

extern "C" void kernel_launch(void* const* d_in, const int* in_sizes, int n_in,
                              void* d_out, int out_size, void* d_ws, size_t ws_size,
                              hipStream_t stream)
{
    const float* x       = (const float*)d_in[0];
    const int*   src     = (const int*)d_in[1];            // edge_index[0]
    const int*   dst     = ((const int*)d_in[1]) + GE;     // edge_index[1]
    const float* W_in    = (const float*)d_in[2];
    const float* b_in    = (const float*)d_in[3];
    const float* W_convs = (const float*)d_in[4];          // [3,128,128]
    const float* b_convs = (const float*)d_in[5];          // [3,128]
    const float* W_out   = (const float*)d_in[6];          // [64,512]
    const float* b_out   = (const float*)d_in[7];
    float*       out     = (float*)d_out;                  // [GN,64]

    // d_ws: cat [GN,512] fp32 + pre-converted weight planes (hi/lo bf16)
    float*  cat = (float*)d_ws;
    __bf16* Whi = (__bf16*)(cat + (size_t)GN * 512);
    __bf16* Wlo = Whi + 98304;

    // CSR scratch in d_out (dead until final kernel overwrites it)
    int*  deg       = (int*)d_out;
    int*  row_start = deg + GN;
    int*  cursor    = row_start + GN;
    int*  blockSums = cursor + GN;
    int*  blockOffs = blockSums + 128;
    int2* csr2      = (int2*)(blockOffs + 128);   // 8B-aligned (offset 1201024)

    const dim3 blk(256);
    const dim3 gblk(512);
    const int edge_blocks  = (GE + 255) / 256;
    const int node_blocks  = (GN + 255) / 256;
    const int layer_blocks = (GN + 63) / 64;     // 1563
    const int final_blocks = (GN + 127) / 128;   // 782

    // --- CSR build (graph static; reused by all 3 layers) ---
    hipMemsetAsync(deg, 0, GN * sizeof(int), stream);
    count_deg<<<edge_blocks, blk, 0, stream>>>(dst, deg);
    scan_pass1<<<SCAN_NBLK, blk, 0, stream>>>(deg, row_start, blockSums);
    scan_pass2<<<1, 128, 0, stream>>>(blockSums, blockOffs, SCAN_NBLK);
    scan_pass3<<<node_blocks, blk, 0, stream>>>(row_start, blockOffs, cursor);
    fill_csr<<<edge_blocks, blk, 0, stream>>>(src, dst, cursor, csr2);

    // --- weight pre-conversion (hi/lo bf16 planes) ---
    convert_w<<<(98304 + 255) / 256, blk, 0, stream>>>(W_in, W_convs, W_out, Whi, Wlo);

    // --- input projection -> cat block 0 ---
    gin_layer<false><<<layer_blocks, gblk, 0, stream>>>(
        x, 128, nullptr, nullptr, Whi, Wlo, b_in, cat, 512);

    // --- three fused GIN layers (edge-parallel gather + linear) ---
    for (int i = 0; i < 3; ++i) {
        gin_layer<true><<<layer_blocks, gblk, 0, stream>>>(
            cat + i * 128, 512, row_start, csr2,
            Whi + 16384 + i * 16384, Wlo + 16384 + i * 16384,
            b_convs + (size_t)i * 128, cat + (i + 1) * 128, 512);
    }

    // --- output projection + fused softmax -> d_out ---
    final_gemm_softmax<<<final_blocks, gblk, 0, stream>>>(
        cat, Whi + 65536, Wlo + 65536, b_out, out);
}

// Round 6
// 1660.010 us; speedup vs baseline: 1.0019x; 1.0019x over previous
//
#include <hip/hip_runtime.h>
#include <hip/hip_bf16.h>

#define GN 100000
#define GE 600000
#define SCAN_NBLK 98   // ceil(GN / 1024)

typedef __bf16 bf16x8 __attribute__((ext_vector_type(8)));
typedef __bf16 bf16x4 __attribute__((ext_vector_type(4)));
typedef float  f32x4  __attribute__((ext_vector_type(4)));

// ---------------------------------------------------------------------------
// Weight pre-conversion: fp32 -> (hi, lo) bf16 planes, done ONCE per launch.
// [0,16384) = W_in[128,128]; [16384,65536) = W_convs[3][128][128];
// [65536,98304) = W_out[64,512]. All row-major [OC, K].
// ---------------------------------------------------------------------------
__global__ __launch_bounds__(256) void convert_w(
    const float* __restrict__ Win, const float* __restrict__ Wc,
    const float* __restrict__ Wout,
    __bf16* __restrict__ hi, __bf16* __restrict__ lo)
{
    const int i = blockIdx.x * 256 + threadIdx.x;
    if (i >= 98304) return;
    float v;
    if (i < 16384)      v = Win[i];
    else if (i < 65536) v = Wc[i - 16384];
    else                v = Wout[i - 65536];
    const __bf16 h = (__bf16)v;
    hi[i] = h;
    lo[i] = (__bf16)(v - (float)h);
}

// ---------------------------------------------------------------------------
// Fused GIN layer: C[64-row tile, 128] = (gather(H) if GATHER else H) @ W^T + b
// Phase A: Acc[64][132] fp32 in LDS = self rows; then (GATHER) edge-parallel
//   accumulate: csr2 slice STAGED IN LDS (decouples the csr->H dependent
//   chain that killed r5), items = edge x float4 -> independent coalesced
//   16B loads + 4x ds_add_f32. Chunked at 2048 edges.
// Phase B: A-fragments read fp32 from Acc, hi/lo bf16 split IN REGISTERS;
//   3-term split MFMA (hi*hi + hi*lo + lo*hi); W pre-converted in global.
// Phase C: acc -> Acc (reused, stride 132) -> full-row 512B coalesced stores.
// Block 512 = 8 waves; wave tile 32x32; BM=64, BN=128.
// ---------------------------------------------------------------------------
template<bool GATHER>
__global__ __launch_bounds__(512) void gin_layer(
    const float* __restrict__ H, int ldH,
    const int* __restrict__ row_start,   // [GN] CSR row offsets (by dst)
    const int2* __restrict__ csr2,       // [GE] (src, dst), sorted by dst
    const __bf16* __restrict__ Whi,      // [128,128]
    const __bf16* __restrict__ Wlo,
    const float* __restrict__ bias,      // [128]
    float* __restrict__ C, int ldC)
{
    constexpr int K     = 128;
    constexpr int ALD   = 132;    // fp32 LDS ld: 128 + 4 -> 2-way-free banks, 16B aligned
    constexpr int CHUNK = 2048;   // staged csr2 entries per pass (16 KB)

    __shared__ float Acc[64 * ALD];                 // 33792 B
    __shared__ int2  csrS[GATHER ? CHUNK : 1];

    const int tid  = threadIdx.x;
    const int wave = tid >> 6;
    const int lane = tid & 63;
    const int row0 = blockIdx.x * 64;
    const int wm   = (wave >> 2) * 32;   // 0/32
    const int wn   = (wave & 3) * 32;    // 0/32/64/96
    const int quad = lane >> 4;
    const int l15  = lane & 15;

    // ---- Phase A1: Acc = self rows (coalesced copy) ----
#pragma unroll
    for (int p = 0; p < 4; ++p) {
        const int q  = tid + p * 512;     // float4 index in [0,2048)
        const int r  = q >> 5;            // 32 float4 per row
        const int c4 = (q & 31) * 4;
        float4 v = make_float4(0.f, 0.f, 0.f, 0.f);
        if (row0 + r < GN) v = *(const float4*)(H + (size_t)(row0 + r) * ldH + c4);
        *(float4*)&Acc[r * ALD + c4] = v;
    }
    __syncthreads();

    // ---- Phase A2 (GATHER): edge-parallel accumulate, csr staged in LDS ----
    if (GATHER) {
        const int e0 = row_start[row0];
        const int e1 = (row0 + 64 >= GN) ? GE : row_start[row0 + 64];
        for (int c0 = e0; c0 < e1; c0 += CHUNK) {
            const int n = min(CHUNK, e1 - c0);
            for (int i = tid; i < n; i += 512) csrS[i] = csr2[c0 + i];
            __syncthreads();
            const int ni = n * 32;        // items = edges x 32 float4
            for (int it = tid; it < ni; it += 512) {
                const int2 sd = csrS[it >> 5];
                const int  c4 = (it & 31) * 4;
                const float4 v = *(const float4*)(H + (size_t)sd.x * ldH + c4);
                float* a = &Acc[(sd.y - row0) * ALD + c4];
                atomicAdd(a + 0, v.x);
                atomicAdd(a + 1, v.y);
                atomicAdd(a + 2, v.z);
                atomicAdd(a + 3, v.w);
            }
            __syncthreads();
        }
    }

    // ---- Phase B: MFMA with in-register hi/lo split of A ----
    f32x4 acc[2][2];
#pragma unroll
    for (int i = 0; i < 2; ++i)
#pragma unroll
        for (int j = 0; j < 2; ++j) acc[i][j] = (f32x4)(0.0f);

#pragma unroll
    for (int ks = 0; ks < 4; ++ks) {
        const int kt = ks * 32 + quad * 8;
        bf16x8 ahi[2], alo[2];
#pragma unroll
        for (int mt = 0; mt < 2; ++mt) {
            const float* ap = &Acc[(wm + mt * 16 + l15) * ALD + kt];
            const f32x4 p = *(const f32x4*)ap;
            const f32x4 q = *(const f32x4*)(ap + 4);
#pragma unroll
            for (int e = 0; e < 4; ++e) {
                const __bf16 hp = (__bf16)p[e];
                const __bf16 hq = (__bf16)q[e];
                ahi[mt][e]     = hp;
                ahi[mt][e + 4] = hq;
                alo[mt][e]     = (__bf16)(p[e] - (float)hp);
                alo[mt][e + 4] = (__bf16)(q[e] - (float)hq);
            }
        }
        bf16x8 whi[2], wlo[2];
#pragma unroll
        for (int nt = 0; nt < 2; ++nt) {
            const int n = wn + nt * 16 + l15;
            whi[nt] = *(const bf16x8*)(Whi + (size_t)n * K + kt);
            wlo[nt] = *(const bf16x8*)(Wlo + (size_t)n * K + kt);
        }
#pragma unroll
        for (int mt = 0; mt < 2; ++mt)
#pragma unroll
            for (int nt = 0; nt < 2; ++nt) {
                acc[mt][nt] = __builtin_amdgcn_mfma_f32_16x16x32_bf16(
                    ahi[mt], whi[nt], acc[mt][nt], 0, 0, 0);
                acc[mt][nt] = __builtin_amdgcn_mfma_f32_16x16x32_bf16(
                    ahi[mt], wlo[nt], acc[mt][nt], 0, 0, 0);
                acc[mt][nt] = __builtin_amdgcn_mfma_f32_16x16x32_bf16(
                    alo[mt], whi[nt], acc[mt][nt], 0, 0, 0);
            }
    }
    __syncthreads();

    // ---- Phase C: epilogue via Acc (reused), full-row coalesced stores ----
#pragma unroll
    for (int nt = 0; nt < 2; ++nt) {
        const int col = wn + nt * 16 + l15;
        const float b = bias[col];
#pragma unroll
        for (int mt = 0; mt < 2; ++mt)
#pragma unroll
            for (int r4 = 0; r4 < 4; ++r4)
                Acc[(wm + mt * 16 + quad * 4 + r4) * ALD + col] = acc[mt][nt][r4] + b;
    }
    __syncthreads();
#pragma unroll
    for (int p = 0; p < 4; ++p) {
        const int q  = tid + p * 512;
        const int r  = q >> 5;           // 32 float4 per row
        const int c4 = (q & 31) * 4;
        const int gr = row0 + r;
        if (gr < GN)
            *(float4*)(C + (size_t)gr * ldC + c4) = *(const float4*)&Acc[r * ALD + c4];
    }
}

// ---------------------------------------------------------------------------
// Final projection + fused softmax: out[GN,64] = softmax(cat @ W_out^T + b)
// BM=128, BN=64 (full row per block), K=512 in BK=64 chunks.
// ---------------------------------------------------------------------------
__global__ __launch_bounds__(512, 2) void final_gemm_softmax(
    const float* __restrict__ A,        // cat, ld 512
    const __bf16* __restrict__ Whi,     // [64,512]
    const __bf16* __restrict__ Wlo,
    const float* __restrict__ bias,     // [64]
    float* __restrict__ out)            // [GN,64]
{
    constexpr int K   = 512;
    constexpr int ALD = 72;    // 64 + 8
    constexpr int CLD = 68;    // 64 + 4

    __shared__ char smem_raw[128 * ALD * 2 * 2];   // 36864 B
    __bf16* Ahi = (__bf16*)smem_raw;
    __bf16* Alo = Ahi + 128 * ALD;
    float*  Cst = (float*)smem_raw;                // 128*68*4 = 34816 B

    const int tid  = threadIdx.x;
    const int wave = tid >> 6;
    const int lane = tid & 63;
    const int row0 = blockIdx.x * 128;
    const int wm   = (wave >> 1) * 32;   // 0/32/64/96
    const int wn   = (wave & 1) * 32;    // 0/32
    const int quad = lane >> 4;
    const int l15  = lane & 15;

    f32x4 acc[2][2];
#pragma unroll
    for (int i = 0; i < 2; ++i)
#pragma unroll
        for (int j = 0; j < 2; ++j) acc[i][j] = (f32x4)(0.0f);

    for (int k0 = 0; k0 < K; k0 += 64) {
#pragma unroll
        for (int p = 0; p < 4; ++p) {
            const int q  = tid + p * 512;
            const int f  = q * 4;
            const int r  = f >> 6;       // 64 floats per row-chunk
            const int kc = f & 63;
            float4 v4 = make_float4(0.f, 0.f, 0.f, 0.f);
            const int gr = row0 + r;
            if (gr < GN) v4 = *(const float4*)(A + (size_t)gr * 512 + k0 + kc);
            const __bf16 h0 = (__bf16)v4.x, h1 = (__bf16)v4.y,
                         h2 = (__bf16)v4.z, h3 = (__bf16)v4.w;
            const int idx = r * ALD + kc;
            *(bf16x4*)&Ahi[idx] = (bf16x4){h0, h1, h2, h3};
            *(bf16x4*)&Alo[idx] = (bf16x4){(__bf16)(v4.x - (float)h0),
                                           (__bf16)(v4.y - (float)h1),
                                           (__bf16)(v4.z - (float)h2),
                                           (__bf16)(v4.w - (float)h3)};
        }
        __syncthreads();

#pragma unroll
        for (int ks = 0; ks < 2; ++ks) {
            const int kt = ks * 32 + quad * 8;
            bf16x8 ahi[2], alo[2];
#pragma unroll
            for (int mt = 0; mt < 2; ++mt) {
                const int idx = (wm + mt * 16 + l15) * ALD + kt;
                ahi[mt] = *(const bf16x8*)&Ahi[idx];
                alo[mt] = *(const bf16x8*)&Alo[idx];
            }
            bf16x8 whi[2], wlo[2];
#pragma unroll
            for (int nt = 0; nt < 2; ++nt) {
                const int n = wn + nt * 16 + l15;
                whi[nt] = *(const bf16x8*)(Whi + (size_t)n * K + k0 + kt);
                wlo[nt] = *(const bf16x8*)(Wlo + (size_t)n * K + k0 + kt);
            }
#pragma unroll
            for (int mt = 0; mt < 2; ++mt)
#pragma unroll
                for (int nt = 0; nt < 2; ++nt) {
                    acc[mt][nt] = __builtin_amdgcn_mfma_f32_16x16x32_bf16(
                        ahi[mt], whi[nt], acc[mt][nt], 0, 0, 0);
                    acc[mt][nt] = __builtin_amdgcn_mfma_f32_16x16x32_bf16(
                        ahi[mt], wlo[nt], acc[mt][nt], 0, 0, 0);
                    acc[mt][nt] = __builtin_amdgcn_mfma_f32_16x16x32_bf16(
                        alo[mt], whi[nt], acc[mt][nt], 0, 0, 0);
                }
        }
        __syncthreads();
    }

    // epilogue -> LDS, + bias
#pragma unroll
    for (int nt = 0; nt < 2; ++nt) {
        const int col = wn + nt * 16 + l15;
        const float b = bias[col];
#pragma unroll
        for (int mt = 0; mt < 2; ++mt)
#pragma unroll
            for (int r4 = 0; r4 < 4; ++r4)
                Cst[(wm + mt * 16 + quad * 4 + r4) * CLD + col] = acc[mt][nt][r4] + b;
    }
    __syncthreads();

    // fused softmax: 8 waves x 16 rows, one wave per row, 64 lanes = 64 cols
    for (int i = 0; i < 16; ++i) {
        const int r = wave * 16 + i;
        const float v = Cst[r * CLD + lane];
        float m = v;
#pragma unroll
        for (int off = 32; off > 0; off >>= 1) m = fmaxf(m, __shfl_xor(m, off));
        const float e = __expf(v - m);
        float s = e;
#pragma unroll
        for (int off = 32; off > 0; off >>= 1) s += __shfl_xor(s, off);
        const int gr = row0 + r;
        if (gr < GN) out[(size_t)gr * 64 + lane] = e / s;
    }
}

// ---------------------------------------------------------------------------
// CSR construction (graph static; built once per launch, used 3x)
// ---------------------------------------------------------------------------
__global__ __launch_bounds__(256) void count_deg(const int* __restrict__ dst,
                                                 int* __restrict__ deg)
{
    const int e = blockIdx.x * 256 + threadIdx.x;
    if (e < GE) atomicAdd(&deg[dst[e]], 1);
}

__global__ __launch_bounds__(256) void scan_pass1(const int* __restrict__ deg,
                                                  int* __restrict__ excl,
                                                  int* __restrict__ blockSums)
{
    __shared__ int s[256];
    const int t = threadIdx.x;
    const int base = blockIdx.x * 1024 + t * 4;

    int4 v = make_int4(0, 0, 0, 0);
    if (base + 3 < GN) {
        v = *(const int4*)(deg + base);
    } else {
        if (base + 0 < GN) v.x = deg[base + 0];
        if (base + 1 < GN) v.y = deg[base + 1];
        if (base + 2 < GN) v.z = deg[base + 2];
        if (base + 3 < GN) v.w = deg[base + 3];
    }
    const int mysum = v.x + v.y + v.z + v.w;
    s[t] = mysum;
    __syncthreads();
    for (int off = 1; off < 256; off <<= 1) {
        const int val = (t >= off) ? s[t - off] : 0;
        __syncthreads();
        s[t] += val;
        __syncthreads();
    }
    int4 o;
    o.x = s[t] - mysum;
    o.y = o.x + v.x;
    o.z = o.y + v.y;
    o.w = o.z + v.z;
    if (base + 3 < GN) {
        *(int4*)(excl + base) = o;
    } else {
        if (base + 0 < GN) excl[base + 0] = o.x;
        if (base + 1 < GN) excl[base + 1] = o.y;
        if (base + 2 < GN) excl[base + 2] = o.z;
        if (base + 3 < GN) excl[base + 3] = o.w;
    }
    if (t == 255) blockSums[blockIdx.x] = s[255];
}

__global__ __launch_bounds__(128) void scan_pass2(const int* __restrict__ blockSums,
                                                  int* __restrict__ blockOffs, int n)
{
    __shared__ int s[128];
    const int t = threadIdx.x;
    const int v = (t < n) ? blockSums[t] : 0;
    s[t] = v;
    __syncthreads();
    for (int off = 1; off < 128; off <<= 1) {
        const int val = (t >= off) ? s[t - off] : 0;
        __syncthreads();
        s[t] += val;
        __syncthreads();
    }
    if (t < n) blockOffs[t] = s[t] - v;
}

__global__ __launch_bounds__(256) void scan_pass3(int* __restrict__ excl,
                                                  const int* __restrict__ blockOffs,
                                                  int* __restrict__ cursor)
{
    const int i = blockIdx.x * 256 + threadIdx.x;
    if (i >= GN) return;
    const int v = excl[i] + blockOffs[i >> 10];
    excl[i]   = v;   // row_start
    cursor[i] = v;   // running cursor for fill
}

__global__ __launch_bounds__(256) void fill_csr(const int* __restrict__ src,
                                                const int* __restrict__ dst,
                                                int* __restrict__ cursor,
                                                int2* __restrict__ csr2)
{
    const int e = blockIdx.x * 256 + threadIdx.x;
    if (e >= GE) return;
    const int d = dst[e];
    const int pos = atomicAdd(&cursor[d], 1);
    csr2[pos] = make_int2(src[e], d);
}

extern "C" void kernel_launch(void* const* d_in, const int* in_sizes, int n_in,
                              void* d_out, int out_size, void* d_ws, size_t ws_size,
                              hipStream_t stream)
{
    const float* x       = (const float*)d_in[0];
    const int*   src     = (const int*)d_in[1];            // edge_index[0]
    const int*   dst     = ((const int*)d_in[1]) + GE;     // edge_index[1]
    const float* W_in    = (const float*)d_in[2];
    const float* b_in    = (const float*)d_in[3];
    const float* W_convs = (const float*)d_in[4];          // [3,128,128]
    const float* b_convs = (const float*)d_in[5];          // [3,128]
    const float* W_out   = (const float*)d_in[6];          // [64,512]
    const float* b_out   = (const float*)d_in[7];
    float*       out     = (float*)d_out;                  // [GN,64]

    // d_ws: cat [GN,512] fp32 + pre-converted weight planes (hi/lo bf16)
    float*  cat = (float*)d_ws;
    __bf16* Whi = (__bf16*)(cat + (size_t)GN * 512);
    __bf16* Wlo = Whi + 98304;

    // CSR scratch in d_out (dead until final kernel overwrites it)
    int*  deg       = (int*)d_out;
    int*  row_start = deg + GN;
    int*  cursor    = row_start + GN;
    int*  blockSums = cursor + GN;
    int*  blockOffs = blockSums + 128;
    int2* csr2      = (int2*)(blockOffs + 128);   // 8B-aligned

    const dim3 blk(256);
    const dim3 gblk(512);
    const int edge_blocks  = (GE + 255) / 256;
    const int node_blocks  = (GN + 255) / 256;
    const int layer_blocks = (GN + 63) / 64;     // 1563
    const int final_blocks = (GN + 127) / 128;   // 782

    // --- CSR build (graph static; reused by all 3 layers) ---
    hipMemsetAsync(deg, 0, GN * sizeof(int), stream);
    count_deg<<<edge_blocks, blk, 0, stream>>>(dst, deg);
    scan_pass1<<<SCAN_NBLK, blk, 0, stream>>>(deg, row_start, blockSums);
    scan_pass2<<<1, 128, 0, stream>>>(blockSums, blockOffs, SCAN_NBLK);
    scan_pass3<<<node_blocks, blk, 0, stream>>>(row_start, blockOffs, cursor);
    fill_csr<<<edge_blocks, blk, 0, stream>>>(src, dst, cursor, csr2);

    // --- weight pre-conversion (hi/lo bf16 planes) ---
    convert_w<<<(98304 + 255) / 256, blk, 0, stream>>>(W_in, W_convs, W_out, Whi, Wlo);

    // --- input projection -> cat block 0 ---
    gin_layer<false><<<layer_blocks, gblk, 0, stream>>>(
        x, 128, nullptr, nullptr, Whi, Wlo, b_in, cat, 512);

    // --- three fused GIN layers (LDS-staged edge-parallel gather + linear) ---
    for (int i = 0; i < 3; ++i) {
        gin_layer<true><<<layer_blocks, gblk, 0, stream>>>(
            cat + i * 128, 512, row_start, csr2,
            Whi + 16384 + i * 16384, Wlo + 16384 + i * 16384,
            b_convs + (size_t)i * 128, cat + (i + 1) * 128, 512);
    }

    // --- output projection + fused softmax -> d_out ---
    final_gemm_softmax<<<final_blocks, gblk, 0, stream>>>(
        cat, Whi + 65536, Wlo + 65536, b_out, out);
}

// Round 7
// 632.753 us; speedup vs baseline: 2.6285x; 2.6235x over previous
//
#include <hip/hip_runtime.h>
#include <hip/hip_bf16.h>

#define GN 100000
#define GE 600000
#define SCAN_NBLK 98   // ceil(GN / 1024)

typedef __bf16 bf16x8 __attribute__((ext_vector_type(8)));
typedef __bf16 bf16x4 __attribute__((ext_vector_type(4)));
typedef float  f32x4  __attribute__((ext_vector_type(4)));

// ---------------------------------------------------------------------------
// Weight pre-conversion: fp32 -> (hi, lo) bf16 planes, done ONCE per launch.
// [0,16384) = W_in[128,128]; [16384,65536) = W_convs[3][128][128];
// [65536,98304) = W_out[64,512]. All row-major [OC, K].
// ---------------------------------------------------------------------------
__global__ __launch_bounds__(256) void convert_w(
    const float* __restrict__ Win, const float* __restrict__ Wc,
    const float* __restrict__ Wout,
    __bf16* __restrict__ hi, __bf16* __restrict__ lo)
{
    const int i = blockIdx.x * 256 + threadIdx.x;
    if (i >= 98304) return;
    float v;
    if (i < 16384)      v = Win[i];
    else if (i < 65536) v = Wc[i - 16384];
    else                v = Wout[i - 65536];
    const __bf16 h = (__bf16)v;
    hi[i] = h;
    lo[i] = (__bf16)(v - (float)h);
}

// ---------------------------------------------------------------------------
// Fused GIN layer: C[64-row tile, 128] = (gather(H) if GATHER else H) @ W^T + b
//
// Phase A: Acc[64][132] fp32 in LDS = self rows. (GATHER): NO ATOMICS —
//   r5/r6 post-mortem: 76.8M ds_add_f32 RMW ops = ~465 us at ~4 cyc/op on the
//   LDS pipe, invisible in VALU/conflict counters. Instead each wave owns 8
//   rows processed CONCURRENTLY: 8 register accumulators (float2/lane),
//   k-step loop unrolled x2 -> 16 independent H-row loads in flight per wave
//   (vs r4's 2). Per-row guards are wave-uniform. Final add into Acc is an
//   owned (lane-exclusive) LDS RMW, no atomic.
// Phase B: A-fragments read fp32 from Acc, hi/lo bf16 split in registers;
//   3-term split MFMA (hi*hi + hi*lo + lo*hi); W pre-converted in global.
// Phase C: acc -> Acc (reused, stride 132) -> full-row 512B coalesced stores.
// Block 512 = 8 waves; wave tile 32x32; BM=64, BN=128.
// ---------------------------------------------------------------------------
template<bool GATHER>
__global__ __launch_bounds__(512) void gin_layer(
    const float* __restrict__ H, int ldH,
    const int* __restrict__ row_start,   // [GN] CSR row offsets (by dst)
    const int* __restrict__ deg,         // [GN] degrees
    const int* __restrict__ csr,         // [GE] src ids, grouped by dst
    const __bf16* __restrict__ Whi,      // [128,128]
    const __bf16* __restrict__ Wlo,
    const float* __restrict__ bias,      // [128]
    float* __restrict__ C, int ldC)
{
    constexpr int K   = 128;
    constexpr int ALD = 132;    // fp32 LDS ld: 128 + 4 -> 2-way-free banks, 16B aligned

    __shared__ float Acc[64 * ALD];      // 33792 B

    const int tid  = threadIdx.x;
    const int wave = tid >> 6;
    const int lane = tid & 63;
    const int row0 = blockIdx.x * 64;
    const int wm   = (wave >> 2) * 32;   // 0/32
    const int wn   = (wave & 3) * 32;    // 0/32/64/96
    const int quad = lane >> 4;
    const int l15  = lane & 15;

    // ---- Phase A1: Acc = self rows (coalesced copy) ----
#pragma unroll
    for (int p = 0; p < 4; ++p) {
        const int q  = tid + p * 512;     // float4 index in [0,2048)
        const int r  = q >> 5;            // 32 float4 per row
        const int c4 = (q & 31) * 4;
        float4 v = make_float4(0.f, 0.f, 0.f, 0.f);
        if (row0 + r < GN) v = *(const float4*)(H + (size_t)(row0 + r) * ldH + c4);
        *(float4*)&Acc[r * ALD + c4] = v;
    }

    // ---- Phase A2 (GATHER): 8 rows per wave, processed concurrently ----
    if (GATHER) {
        const int j = lane * 2;           // lane owns float2 column of each row
        float2 acc8[8];
        int start8[8], deg8[8];
#pragma unroll
        for (int r = 0; r < 8; ++r) {
            acc8[r] = make_float2(0.f, 0.f);
            const int v = row0 + wave * 8 + r;
            start8[r] = (v < GN) ? row_start[v] : 0;
            deg8[r]   = (v < GN) ? deg[v] : 0;
        }

        bool active = true;
        for (int k = 0; active; k += 2) {
            active = false;
            int sA[8], sB[8];
#pragma unroll
            for (int r = 0; r < 8; ++r) {
                sA[r] = (k     < deg8[r]) ? csr[start8[r] + k]     : -1;
                sB[r] = (k + 1 < deg8[r]) ? csr[start8[r] + k + 1] : -1;
            }
#pragma unroll
            for (int r = 0; r < 8; ++r)
                if (sA[r] >= 0) {
                    const float2 t = *(const float2*)(H + (size_t)sA[r] * ldH + j);
                    acc8[r].x += t.x; acc8[r].y += t.y;
                    active = true;
                }
#pragma unroll
            for (int r = 0; r < 8; ++r)
                if (sB[r] >= 0) {
                    const float2 t = *(const float2*)(H + (size_t)sB[r] * ldH + j);
                    acc8[r].x += t.x; acc8[r].y += t.y;
                    active = true;
                }
        }

        __syncthreads();   // A1 writes complete everywhere before owned RMW
#pragma unroll
        for (int r = 0; r < 8; ++r) {
            float* a = &Acc[(wave * 8 + r) * ALD + j];
            a[0] += acc8[r].x;
            a[1] += acc8[r].y;
        }
    }
    __syncthreads();

    // ---- Phase B: MFMA with in-register hi/lo split of A ----
    f32x4 acc[2][2];
#pragma unroll
    for (int i = 0; i < 2; ++i)
#pragma unroll
        for (int j = 0; j < 2; ++j) acc[i][j] = (f32x4)(0.0f);

#pragma unroll
    for (int ks = 0; ks < 4; ++ks) {
        const int kt = ks * 32 + quad * 8;
        bf16x8 ahi[2], alo[2];
#pragma unroll
        for (int mt = 0; mt < 2; ++mt) {
            const float* ap = &Acc[(wm + mt * 16 + l15) * ALD + kt];
            const f32x4 p = *(const f32x4*)ap;
            const f32x4 q = *(const f32x4*)(ap + 4);
#pragma unroll
            for (int e = 0; e < 4; ++e) {
                const __bf16 hp = (__bf16)p[e];
                const __bf16 hq = (__bf16)q[e];
                ahi[mt][e]     = hp;
                ahi[mt][e + 4] = hq;
                alo[mt][e]     = (__bf16)(p[e] - (float)hp);
                alo[mt][e + 4] = (__bf16)(q[e] - (float)hq);
            }
        }
        bf16x8 whi[2], wlo[2];
#pragma unroll
        for (int nt = 0; nt < 2; ++nt) {
            const int n = wn + nt * 16 + l15;
            whi[nt] = *(const bf16x8*)(Whi + (size_t)n * K + kt);
            wlo[nt] = *(const bf16x8*)(Wlo + (size_t)n * K + kt);
        }
#pragma unroll
        for (int mt = 0; mt < 2; ++mt)
#pragma unroll
            for (int nt = 0; nt < 2; ++nt) {
                acc[mt][nt] = __builtin_amdgcn_mfma_f32_16x16x32_bf16(
                    ahi[mt], whi[nt], acc[mt][nt], 0, 0, 0);
                acc[mt][nt] = __builtin_amdgcn_mfma_f32_16x16x32_bf16(
                    ahi[mt], wlo[nt], acc[mt][nt], 0, 0, 0);
                acc[mt][nt] = __builtin_amdgcn_mfma_f32_16x16x32_bf16(
                    alo[mt], whi[nt], acc[mt][nt], 0, 0, 0);
            }
    }
    __syncthreads();

    // ---- Phase C: epilogue via Acc (reused), full-row coalesced stores ----
#pragma unroll
    for (int nt = 0; nt < 2; ++nt) {
        const int col = wn + nt * 16 + l15;
        const float b = bias[col];
#pragma unroll
        for (int mt = 0; mt < 2; ++mt)
#pragma unroll
            for (int r4 = 0; r4 < 4; ++r4)
                Acc[(wm + mt * 16 + quad * 4 + r4) * ALD + col] = acc[mt][nt][r4] + b;
    }
    __syncthreads();
#pragma unroll
    for (int p = 0; p < 4; ++p) {
        const int q  = tid + p * 512;
        const int r  = q >> 5;           // 32 float4 per row
        const int c4 = (q & 31) * 4;
        const int gr = row0 + r;
        if (gr < GN)
            *(float4*)(C + (size_t)gr * ldC + c4) = *(const float4*)&Acc[r * ALD + c4];
    }
}

// ---------------------------------------------------------------------------
// Final projection + fused softmax: out[GN,64] = softmax(cat @ W_out^T + b)
// BM=128, BN=64 (full row per block), K=512 in BK=64 chunks.
// ---------------------------------------------------------------------------
__global__ __launch_bounds__(512, 2) void final_gemm_softmax(
    const float* __restrict__ A,        // cat, ld 512
    const __bf16* __restrict__ Whi,     // [64,512]
    const __bf16* __restrict__ Wlo,
    const float* __restrict__ bias,     // [64]
    float* __restrict__ out)            // [GN,64]
{
    constexpr int K   = 512;
    constexpr int ALD = 72;    // 64 + 8
    constexpr int CLD = 68;    // 64 + 4

    __shared__ char smem_raw[128 * ALD * 2 * 2];   // 36864 B
    __bf16* Ahi = (__bf16*)smem_raw;
    __bf16* Alo = Ahi + 128 * ALD;
    float*  Cst = (float*)smem_raw;                // 128*68*4 = 34816 B

    const int tid  = threadIdx.x;
    const int wave = tid >> 6;
    const int lane = tid & 63;
    const int row0 = blockIdx.x * 128;
    const int wm   = (wave >> 1) * 32;   // 0/32/64/96
    const int wn   = (wave & 1) * 32;    // 0/32
    const int quad = lane >> 4;
    const int l15  = lane & 15;

    f32x4 acc[2][2];
#pragma unroll
    for (int i = 0; i < 2; ++i)
#pragma unroll
        for (int j = 0; j < 2; ++j) acc[i][j] = (f32x4)(0.0f);

    for (int k0 = 0; k0 < K; k0 += 64) {
#pragma unroll
        for (int p = 0; p < 4; ++p) {
            const int q  = tid + p * 512;
            const int f  = q * 4;
            const int r  = f >> 6;       // 64 floats per row-chunk
            const int kc = f & 63;
            float4 v4 = make_float4(0.f, 0.f, 0.f, 0.f);
            const int gr = row0 + r;
            if (gr < GN) v4 = *(const float4*)(A + (size_t)gr * 512 + k0 + kc);
            const __bf16 h0 = (__bf16)v4.x, h1 = (__bf16)v4.y,
                         h2 = (__bf16)v4.z, h3 = (__bf16)v4.w;
            const int idx = r * ALD + kc;
            *(bf16x4*)&Ahi[idx] = (bf16x4){h0, h1, h2, h3};
            *(bf16x4*)&Alo[idx] = (bf16x4){(__bf16)(v4.x - (float)h0),
                                           (__bf16)(v4.y - (float)h1),
                                           (__bf16)(v4.z - (float)h2),
                                           (__bf16)(v4.w - (float)h3)};
        }
        __syncthreads();

#pragma unroll
        for (int ks = 0; ks < 2; ++ks) {
            const int kt = ks * 32 + quad * 8;
            bf16x8 ahi[2], alo[2];
#pragma unroll
            for (int mt = 0; mt < 2; ++mt) {
                const int idx = (wm + mt * 16 + l15) * ALD + kt;
                ahi[mt] = *(const bf16x8*)&Ahi[idx];
                alo[mt] = *(const bf16x8*)&Alo[idx];
            }
            bf16x8 whi[2], wlo[2];
#pragma unroll
            for (int nt = 0; nt < 2; ++nt) {
                const int n = wn + nt * 16 + l15;
                whi[nt] = *(const bf16x8*)(Whi + (size_t)n * K + k0 + kt);
                wlo[nt] = *(const bf16x8*)(Wlo + (size_t)n * K + k0 + kt);
            }
#pragma unroll
            for (int mt = 0; mt < 2; ++mt)
#pragma unroll
                for (int nt = 0; nt < 2; ++nt) {
                    acc[mt][nt] = __builtin_amdgcn_mfma_f32_16x16x32_bf16(
                        ahi[mt], whi[nt], acc[mt][nt], 0, 0, 0);
                    acc[mt][nt] = __builtin_amdgcn_mfma_f32_16x16x32_bf16(
                        ahi[mt], wlo[nt], acc[mt][nt], 0, 0, 0);
                    acc[mt][nt] = __builtin_amdgcn_mfma_f32_16x16x32_bf16(
                        alo[mt], whi[nt], acc[mt][nt], 0, 0, 0);
                }
        }
        __syncthreads();
    }

    // epilogue -> LDS, + bias
#pragma unroll
    for (int nt = 0; nt < 2; ++nt) {
        const int col = wn + nt * 16 + l15;
        const float b = bias[col];
#pragma unroll
        for (int mt = 0; mt < 2; ++mt)
#pragma unroll
            for (int r4 = 0; r4 < 4; ++r4)
                Cst[(wm + mt * 16 + quad * 4 + r4) * CLD + col] = acc[mt][nt][r4] + b;
    }
    __syncthreads();

    // fused softmax: 8 waves x 16 rows, one wave per row, 64 lanes = 64 cols
    for (int i = 0; i < 16; ++i) {
        const int r = wave * 16 + i;
        const float v = Cst[r * CLD + lane];
        float m = v;
#pragma unroll
        for (int off = 32; off > 0; off >>= 1) m = fmaxf(m, __shfl_xor(m, off));
        const float e = __expf(v - m);
        float s = e;
#pragma unroll
        for (int off = 32; off > 0; off >>= 1) s += __shfl_xor(s, off);
        const int gr = row0 + r;
        if (gr < GN) out[(size_t)gr * 64 + lane] = e / s;
    }
}

// ---------------------------------------------------------------------------
// CSR construction (graph static; built once per launch, used 3x)
// ---------------------------------------------------------------------------
__global__ __launch_bounds__(256) void count_deg(const int* __restrict__ dst,
                                                 int* __restrict__ deg)
{
    const int e = blockIdx.x * 256 + threadIdx.x;
    if (e < GE) atomicAdd(&deg[dst[e]], 1);
}

__global__ __launch_bounds__(256) void scan_pass1(const int* __restrict__ deg,
                                                  int* __restrict__ excl,
                                                  int* __restrict__ blockSums)
{
    __shared__ int s[256];
    const int t = threadIdx.x;
    const int base = blockIdx.x * 1024 + t * 4;

    int4 v = make_int4(0, 0, 0, 0);
    if (base + 3 < GN) {
        v = *(const int4*)(deg + base);
    } else {
        if (base + 0 < GN) v.x = deg[base + 0];
        if (base + 1 < GN) v.y = deg[base + 1];
        if (base + 2 < GN) v.z = deg[base + 2];
        if (base + 3 < GN) v.w = deg[base + 3];
    }
    const int mysum = v.x + v.y + v.z + v.w;
    s[t] = mysum;
    __syncthreads();
    for (int off = 1; off < 256; off <<= 1) {
        const int val = (t >= off) ? s[t - off] : 0;
        __syncthreads();
        s[t] += val;
        __syncthreads();
    }
    int4 o;
    o.x = s[t] - mysum;
    o.y = o.x + v.x;
    o.z = o.y + v.y;
    o.w = o.z + v.z;
    if (base + 3 < GN) {
        *(int4*)(excl + base) = o;
    } else {
        if (base + 0 < GN) excl[base + 0] = o.x;
        if (base + 1 < GN) excl[base + 1] = o.y;
        if (base + 2 < GN) excl[base + 2] = o.z;
        if (base + 3 < GN) excl[base + 3] = o.w;
    }
    if (t == 255) blockSums[blockIdx.x] = s[255];
}

__global__ __launch_bounds__(128) void scan_pass2(const int* __restrict__ blockSums,
                                                  int* __restrict__ blockOffs, int n)
{
    __shared__ int s[128];
    const int t = threadIdx.x;
    const int v = (t < n) ? blockSums[t] : 0;
    s[t] = v;
    __syncthreads();
    for (int off = 1; off < 128; off <<= 1) {
        const int val = (t >= off) ? s[t - off] : 0;
        __syncthreads();
        s[t] += val;
        __syncthreads();
    }
    if (t < n) blockOffs[t] = s[t] - v;
}

__global__ __launch_bounds__(256) void scan_pass3(int* __restrict__ excl,
                                                  const int* __restrict__ blockOffs,
                                                  int* __restrict__ cursor)
{
    const int i = blockIdx.x * 256 + threadIdx.x;
    if (i >= GN) return;
    const int v = excl[i] + blockOffs[i >> 10];
    excl[i]   = v;   // row_start
    cursor[i] = v;   // running cursor for fill
}

__global__ __launch_bounds__(256) void fill_csr(const int* __restrict__ src,
                                                const int* __restrict__ dst,
                                                int* __restrict__ cursor,
                                                int* __restrict__ csr)
{
    const int e = blockIdx.x * 256 + threadIdx.x;
    if (e >= GE) return;
    const int pos = atomicAdd(&cursor[dst[e]], 1);
    csr[pos] = src[e];
}

extern "C" void kernel_launch(void* const* d_in, const int* in_sizes, int n_in,
                              void* d_out, int out_size, void* d_ws, size_t ws_size,
                              hipStream_t stream)
{
    const float* x       = (const float*)d_in[0];
    const int*   src     = (const int*)d_in[1];            // edge_index[0]
    const int*   dst     = ((const int*)d_in[1]) + GE;     // edge_index[1]
    const float* W_in    = (const float*)d_in[2];
    const float* b_in    = (const float*)d_in[3];
    const float* W_convs = (const float*)d_in[4];          // [3,128,128]
    const float* b_convs = (const float*)d_in[5];          // [3,128]
    const float* W_out   = (const float*)d_in[6];          // [64,512]
    const float* b_out   = (const float*)d_in[7];
    float*       out     = (float*)d_out;                  // [GN,64]

    // d_ws: cat [GN,512] fp32 + pre-converted weight planes (hi/lo bf16)
    float*  cat = (float*)d_ws;
    __bf16* Whi = (__bf16*)(cat + (size_t)GN * 512);
    __bf16* Wlo = Whi + 98304;

    // CSR scratch in d_out (dead until final kernel overwrites it)
    int* deg       = (int*)d_out;
    int* row_start = deg + GN;
    int* cursor    = row_start + GN;
    int* blockSums = cursor + GN;
    int* blockOffs = blockSums + 128;
    int* csr       = blockOffs + 128;

    const dim3 blk(256);
    const dim3 gblk(512);
    const int edge_blocks  = (GE + 255) / 256;
    const int node_blocks  = (GN + 255) / 256;
    const int layer_blocks = (GN + 63) / 64;     // 1563
    const int final_blocks = (GN + 127) / 128;   // 782

    // --- CSR build (graph static; reused by all 3 layers) ---
    hipMemsetAsync(deg, 0, GN * sizeof(int), stream);
    count_deg<<<edge_blocks, blk, 0, stream>>>(dst, deg);
    scan_pass1<<<SCAN_NBLK, blk, 0, stream>>>(deg, row_start, blockSums);
    scan_pass2<<<1, 128, 0, stream>>>(blockSums, blockOffs, SCAN_NBLK);
    scan_pass3<<<node_blocks, blk, 0, stream>>>(row_start, blockOffs, cursor);
    fill_csr<<<edge_blocks, blk, 0, stream>>>(src, dst, cursor, csr);

    // --- weight pre-conversion (hi/lo bf16 planes) ---
    convert_w<<<(98304 + 255) / 256, blk, 0, stream>>>(W_in, W_convs, W_out, Whi, Wlo);

    // --- input projection -> cat block 0 ---
    gin_layer<false><<<layer_blocks, gblk, 0, stream>>>(
        x, 128, nullptr, nullptr, nullptr, Whi, Wlo, b_in, cat, 512);

    // --- three fused GIN layers (register-owned gather, 16-deep MLP) ---
    for (int i = 0; i < 3; ++i) {
        gin_layer<true><<<layer_blocks, gblk, 0, stream>>>(
            cat + i * 128, 512, row_start, deg, csr,
            Whi + 16384 + i * 16384, Wlo + 16384 + i * 16384,
            b_convs + (size_t)i * 128, cat + (i + 1) * 128, 512);
    }

    // --- output projection + fused softmax -> d_out ---
    final_gemm_softmax<<<final_blocks, gblk, 0, stream>>>(
        cat, Whi + 65536, Wlo + 65536, b_out, out);
}

// Round 8
// 596.534 us; speedup vs baseline: 2.7881x; 1.0607x over previous
//
#include <hip/hip_runtime.h>
#include <hip/hip_bf16.h>

#define GN 100000
#define GE 600000
#define SCAN_NBLK 98   // ceil(GN / 1024)

typedef __bf16 bf16x8 __attribute__((ext_vector_type(8)));
typedef __bf16 bf16x4 __attribute__((ext_vector_type(4)));
typedef float  f32x4  __attribute__((ext_vector_type(4)));

// ---------------------------------------------------------------------------
// Weight pre-conversion: fp32 -> (hi, lo) bf16 planes, done ONCE per launch.
// [0,16384) = W_in[128,128]; [16384,65536) = W_convs[3][128][128];
// [65536,98304) = W_out[64,512]. All row-major [OC, K].
// ---------------------------------------------------------------------------
__global__ __launch_bounds__(256) void convert_w(
    const float* __restrict__ Win, const float* __restrict__ Wc,
    const float* __restrict__ Wout,
    __bf16* __restrict__ hi, __bf16* __restrict__ lo)
{
    const int i = blockIdx.x * 256 + threadIdx.x;
    if (i >= 98304) return;
    float v;
    if (i < 16384)      v = Win[i];
    else if (i < 65536) v = Wc[i - 16384];
    else                v = Wout[i - 65536];
    const __bf16 h = (__bf16)v;
    hi[i] = h;
    lo[i] = (__bf16)(v - (float)h);
}

// ---------------------------------------------------------------------------
// Fused GIN layer: C[64-row tile, 128] = (gather(H) if GATHER else H) @ W^T + b
//
// Phase A2 (GATHER) — r7 post-mortem: VGPR_Count=40 proved the compiler
//   serialized the guarded loads (each `if(s>=0){load;add}` is its own BB ->
//   load+waitcnt+use chains, MLP~2). Fix: BRANCHLESS + SOFTWARE-PIPELINED.
//   All loads unconditional (csr index clamped to a valid entry, H index
//   clamped to [0,GN)), accumulate masked by fma with 0/1. Next iteration's
//   8 csr loads issue BEFORE this iteration's 8 H loads -> steady state pays
//   only H latency for 8 independent 512B row reads per wave per iteration.
//   __launch_bounds__(512,4): cap 128 VGPR so the 8 results + 8 addrs live.
// Phase B: A-fragments read fp32 from Acc, hi/lo bf16 split in registers;
//   3-term split MFMA (hi*hi + hi*lo + lo*hi); W pre-converted in global.
// Phase C: acc -> Acc (reused, stride 132) -> full-row 512B coalesced stores.
// Block 512 = 8 waves; wave tile 32x32; BM=64, BN=128.
// ---------------------------------------------------------------------------
template<bool GATHER>
__global__ __launch_bounds__(512, 4) void gin_layer(
    const float* __restrict__ H, int ldH,
    const int* __restrict__ row_start,   // [GN] CSR row offsets (by dst)
    const int* __restrict__ deg,         // [GN] degrees
    const int* __restrict__ csr,         // [GE] src ids, grouped by dst
    const __bf16* __restrict__ Whi,      // [128,128]
    const __bf16* __restrict__ Wlo,
    const float* __restrict__ bias,      // [128]
    float* __restrict__ C, int ldC)
{
    constexpr int K   = 128;
    constexpr int ALD = 132;    // fp32 LDS ld: 128 + 4 -> 2-way-free banks, 16B aligned

    __shared__ float Acc[64 * ALD];      // 33792 B

    const int tid  = threadIdx.x;
    const int wave = tid >> 6;
    const int lane = tid & 63;
    const int row0 = blockIdx.x * 64;
    const int wm   = (wave >> 2) * 32;   // 0/32
    const int wn   = (wave & 3) * 32;    // 0/32/64/96
    const int quad = lane >> 4;
    const int l15  = lane & 15;

    // ---- Phase A1: Acc = self rows (coalesced copy) ----
#pragma unroll
    for (int p = 0; p < 4; ++p) {
        const int q  = tid + p * 512;     // float4 index in [0,2048)
        const int r  = q >> 5;            // 32 float4 per row
        const int c4 = (q & 31) * 4;
        float4 v = make_float4(0.f, 0.f, 0.f, 0.f);
        if (row0 + r < GN) v = *(const float4*)(H + (size_t)(row0 + r) * ldH + c4);
        *(float4*)&Acc[r * ALD + c4] = v;
    }

    // ---- Phase A2 (GATHER): branchless pipelined 8-row gather ----
    if (GATHER) {
        const int j = lane * 2;           // lane owns float2 column of each row
        float2 acc8[8];
        int start8[8], deg8[8];
        int maxd = 0;
#pragma unroll
        for (int r = 0; r < 8; ++r) {
            acc8[r] = make_float2(0.f, 0.f);
            const int v = row0 + wave * 8 + r;
            start8[r] = (v < GN) ? row_start[v] : 0;
            deg8[r]   = (v < GN) ? deg[v] : 0;
            maxd = max(maxd, deg8[r]);
        }

        // prologue: neighbor ids for k=0 (clamped -> always a valid address)
        int scur[8];
#pragma unroll
        for (int r = 0; r < 8; ++r) {
            int s = csr[start8[r]];                 // in-buffer even if deg==0
            scur[r] = min(max(s, 0), GN - 1);       // clamp (masked rows)
        }

        for (int k = 0; k < maxd; ++k) {
            // issue NEXT k's csr loads first (overlap with H latency)
            int snext[8];
#pragma unroll
            for (int r = 0; r < 8; ++r) {
                const int kk = max(min(k + 1, deg8[r] - 1), 0);
                snext[r] = csr[start8[r] + kk];
            }
            // 8 independent unconditional H row loads (batched by compiler)
            float2 t[8];
#pragma unroll
            for (int r = 0; r < 8; ++r)
                t[r] = *(const float2*)(H + (size_t)scur[r] * ldH + j);
            // masked accumulate + rotate pipeline regs
#pragma unroll
            for (int r = 0; r < 8; ++r) {
                const float m = (k < deg8[r]) ? 1.f : 0.f;
                acc8[r].x = fmaf(m, t[r].x, acc8[r].x);
                acc8[r].y = fmaf(m, t[r].y, acc8[r].y);
                scur[r] = min(max(snext[r], 0), GN - 1);
            }
        }

        __syncthreads();   // A1 writes complete everywhere before owned RMW
#pragma unroll
        for (int r = 0; r < 8; ++r) {
            float* a = &Acc[(wave * 8 + r) * ALD + j];
            a[0] += acc8[r].x;
            a[1] += acc8[r].y;
        }
    }
    __syncthreads();

    // ---- Phase B: MFMA with in-register hi/lo split of A ----
    f32x4 acc[2][2];
#pragma unroll
    for (int i = 0; i < 2; ++i)
#pragma unroll
        for (int j = 0; j < 2; ++j) acc[i][j] = (f32x4)(0.0f);

#pragma unroll
    for (int ks = 0; ks < 4; ++ks) {
        const int kt = ks * 32 + quad * 8;
        bf16x8 ahi[2], alo[2];
#pragma unroll
        for (int mt = 0; mt < 2; ++mt) {
            const float* ap = &Acc[(wm + mt * 16 + l15) * ALD + kt];
            const f32x4 p = *(const f32x4*)ap;
            const f32x4 q = *(const f32x4*)(ap + 4);
#pragma unroll
            for (int e = 0; e < 4; ++e) {
                const __bf16 hp = (__bf16)p[e];
                const __bf16 hq = (__bf16)q[e];
                ahi[mt][e]     = hp;
                ahi[mt][e + 4] = hq;
                alo[mt][e]     = (__bf16)(p[e] - (float)hp);
                alo[mt][e + 4] = (__bf16)(q[e] - (float)hq);
            }
        }
        bf16x8 whi[2], wlo[2];
#pragma unroll
        for (int nt = 0; nt < 2; ++nt) {
            const int n = wn + nt * 16 + l15;
            whi[nt] = *(const bf16x8*)(Whi + (size_t)n * K + kt);
            wlo[nt] = *(const bf16x8*)(Wlo + (size_t)n * K + kt);
        }
#pragma unroll
        for (int mt = 0; mt < 2; ++mt)
#pragma unroll
            for (int nt = 0; nt < 2; ++nt) {
                acc[mt][nt] = __builtin_amdgcn_mfma_f32_16x16x32_bf16(
                    ahi[mt], whi[nt], acc[mt][nt], 0, 0, 0);
                acc[mt][nt] = __builtin_amdgcn_mfma_f32_16x16x32_bf16(
                    ahi[mt], wlo[nt], acc[mt][nt], 0, 0, 0);
                acc[mt][nt] = __builtin_amdgcn_mfma_f32_16x16x32_bf16(
                    alo[mt], whi[nt], acc[mt][nt], 0, 0, 0);
            }
    }
    __syncthreads();

    // ---- Phase C: epilogue via Acc (reused), full-row coalesced stores ----
#pragma unroll
    for (int nt = 0; nt < 2; ++nt) {
        const int col = wn + nt * 16 + l15;
        const float b = bias[col];
#pragma unroll
        for (int mt = 0; mt < 2; ++mt)
#pragma unroll
            for (int r4 = 0; r4 < 4; ++r4)
                Acc[(wm + mt * 16 + quad * 4 + r4) * ALD + col] = acc[mt][nt][r4] + b;
    }
    __syncthreads();
#pragma unroll
    for (int p = 0; p < 4; ++p) {
        const int q  = tid + p * 512;
        const int r  = q >> 5;           // 32 float4 per row
        const int c4 = (q & 31) * 4;
        const int gr = row0 + r;
        if (gr < GN)
            *(float4*)(C + (size_t)gr * ldC + c4) = *(const float4*)&Acc[r * ALD + c4];
    }
}

// ---------------------------------------------------------------------------
// Final projection + fused softmax: out[GN,64] = softmax(cat @ W_out^T + b)
// BM=128, BN=64 (full row per block), K=512 in BK=64 chunks.
// ---------------------------------------------------------------------------
__global__ __launch_bounds__(512, 2) void final_gemm_softmax(
    const float* __restrict__ A,        // cat, ld 512
    const __bf16* __restrict__ Whi,     // [64,512]
    const __bf16* __restrict__ Wlo,
    const float* __restrict__ bias,     // [64]
    float* __restrict__ out)            // [GN,64]
{
    constexpr int K   = 512;
    constexpr int ALD = 72;    // 64 + 8
    constexpr int CLD = 68;    // 64 + 4

    __shared__ char smem_raw[128 * ALD * 2 * 2];   // 36864 B
    __bf16* Ahi = (__bf16*)smem_raw;
    __bf16* Alo = Ahi + 128 * ALD;
    float*  Cst = (float*)smem_raw;                // 128*68*4 = 34816 B

    const int tid  = threadIdx.x;
    const int wave = tid >> 6;
    const int lane = tid & 63;
    const int row0 = blockIdx.x * 128;
    const int wm   = (wave >> 1) * 32;   // 0/32/64/96
    const int wn   = (wave & 1) * 32;    // 0/32
    const int quad = lane >> 4;
    const int l15  = lane & 15;

    f32x4 acc[2][2];
#pragma unroll
    for (int i = 0; i < 2; ++i)
#pragma unroll
        for (int j = 0; j < 2; ++j) acc[i][j] = (f32x4)(0.0f);

    for (int k0 = 0; k0 < K; k0 += 64) {
#pragma unroll
        for (int p = 0; p < 4; ++p) {
            const int q  = tid + p * 512;
            const int f  = q * 4;
            const int r  = f >> 6;       // 64 floats per row-chunk
            const int kc = f & 63;
            float4 v4 = make_float4(0.f, 0.f, 0.f, 0.f);
            const int gr = row0 + r;
            if (gr < GN) v4 = *(const float4*)(A + (size_t)gr * 512 + k0 + kc);
            const __bf16 h0 = (__bf16)v4.x, h1 = (__bf16)v4.y,
                         h2 = (__bf16)v4.z, h3 = (__bf16)v4.w;
            const int idx = r * ALD + kc;
            *(bf16x4*)&Ahi[idx] = (bf16x4){h0, h1, h2, h3};
            *(bf16x4*)&Alo[idx] = (bf16x4){(__bf16)(v4.x - (float)h0),
                                           (__bf16)(v4.y - (float)h1),
                                           (__bf16)(v4.z - (float)h2),
                                           (__bf16)(v4.w - (float)h3)};
        }
        __syncthreads();

#pragma unroll
        for (int ks = 0; ks < 2; ++ks) {
            const int kt = ks * 32 + quad * 8;
            bf16x8 ahi[2], alo[2];
#pragma unroll
            for (int mt = 0; mt < 2; ++mt) {
                const int idx = (wm + mt * 16 + l15) * ALD + kt;
                ahi[mt] = *(const bf16x8*)&Ahi[idx];
                alo[mt] = *(const bf16x8*)&Alo[idx];
            }
            bf16x8 whi[2], wlo[2];
#pragma unroll
            for (int nt = 0; nt < 2; ++nt) {
                const int n = wn + nt * 16 + l15;
                whi[nt] = *(const bf16x8*)(Whi + (size_t)n * K + k0 + kt);
                wlo[nt] = *(const bf16x8*)(Wlo + (size_t)n * K + k0 + kt);
            }
#pragma unroll
            for (int mt = 0; mt < 2; ++mt)
#pragma unroll
                for (int nt = 0; nt < 2; ++nt) {
                    acc[mt][nt] = __builtin_amdgcn_mfma_f32_16x16x32_bf16(
                        ahi[mt], whi[nt], acc[mt][nt], 0, 0, 0);
                    acc[mt][nt] = __builtin_amdgcn_mfma_f32_16x16x32_bf16(
                        ahi[mt], wlo[nt], acc[mt][nt], 0, 0, 0);
                    acc[mt][nt] = __builtin_amdgcn_mfma_f32_16x16x32_bf16(
                        alo[mt], whi[nt], acc[mt][nt], 0, 0, 0);
                }
        }
        __syncthreads();
    }

    // epilogue -> LDS, + bias
#pragma unroll
    for (int nt = 0; nt < 2; ++nt) {
        const int col = wn + nt * 16 + l15;
        const float b = bias[col];
#pragma unroll
        for (int mt = 0; mt < 2; ++mt)
#pragma unroll
            for (int r4 = 0; r4 < 4; ++r4)
                Cst[(wm + mt * 16 + quad * 4 + r4) * CLD + col] = acc[mt][nt][r4] + b;
    }
    __syncthreads();

    // fused softmax: 8 waves x 16 rows, one wave per row, 64 lanes = 64 cols
    for (int i = 0; i < 16; ++i) {
        const int r = wave * 16 + i;
        const float v = Cst[r * CLD + lane];
        float m = v;
#pragma unroll
        for (int off = 32; off > 0; off >>= 1) m = fmaxf(m, __shfl_xor(m, off));
        const float e = __expf(v - m);
        float s = e;
#pragma unroll
        for (int off = 32; off > 0; off >>= 1) s += __shfl_xor(s, off);
        const int gr = row0 + r;
        if (gr < GN) out[(size_t)gr * 64 + lane] = e / s;
    }
}

// ---------------------------------------------------------------------------
// CSR construction (graph static; built once per launch, used 3x)
// ---------------------------------------------------------------------------
__global__ __launch_bounds__(256) void count_deg(const int* __restrict__ dst,
                                                 int* __restrict__ deg)
{
    const int e = blockIdx.x * 256 + threadIdx.x;
    if (e < GE) atomicAdd(&deg[dst[e]], 1);
}

__global__ __launch_bounds__(256) void scan_pass1(const int* __restrict__ deg,
                                                  int* __restrict__ excl,
                                                  int* __restrict__ blockSums)
{
    __shared__ int s[256];
    const int t = threadIdx.x;
    const int base = blockIdx.x * 1024 + t * 4;

    int4 v = make_int4(0, 0, 0, 0);
    if (base + 3 < GN) {
        v = *(const int4*)(deg + base);
    } else {
        if (base + 0 < GN) v.x = deg[base + 0];
        if (base + 1 < GN) v.y = deg[base + 1];
        if (base + 2 < GN) v.z = deg[base + 2];
        if (base + 3 < GN) v.w = deg[base + 3];
    }
    const int mysum = v.x + v.y + v.z + v.w;
    s[t] = mysum;
    __syncthreads();
    for (int off = 1; off < 256; off <<= 1) {
        const int val = (t >= off) ? s[t - off] : 0;
        __syncthreads();
        s[t] += val;
        __syncthreads();
    }
    int4 o;
    o.x = s[t] - mysum;
    o.y = o.x + v.x;
    o.z = o.y + v.y;
    o.w = o.z + v.z;
    if (base + 3 < GN) {
        *(int4*)(excl + base) = o;
    } else {
        if (base + 0 < GN) excl[base + 0] = o.x;
        if (base + 1 < GN) excl[base + 1] = o.y;
        if (base + 2 < GN) excl[base + 2] = o.z;
        if (base + 3 < GN) excl[base + 3] = o.w;
    }
    if (t == 255) blockSums[blockIdx.x] = s[255];
}

__global__ __launch_bounds__(128) void scan_pass2(const int* __restrict__ blockSums,
                                                  int* __restrict__ blockOffs, int n)
{
    __shared__ int s[128];
    const int t = threadIdx.x;
    const int v = (t < n) ? blockSums[t] : 0;
    s[t] = v;
    __syncthreads();
    for (int off = 1; off < 128; off <<= 1) {
        const int val = (t >= off) ? s[t - off] : 0;
        __syncthreads();
        s[t] += val;
        __syncthreads();
    }
    if (t < n) blockOffs[t] = s[t] - v;
}

__global__ __launch_bounds__(256) void scan_pass3(int* __restrict__ excl,
                                                  const int* __restrict__ blockOffs,
                                                  int* __restrict__ cursor)
{
    const int i = blockIdx.x * 256 + threadIdx.x;
    if (i >= GN) return;
    const int v = excl[i] + blockOffs[i >> 10];
    excl[i]   = v;   // row_start
    cursor[i] = v;   // running cursor for fill
}

__global__ __launch_bounds__(256) void fill_csr(const int* __restrict__ src,
                                                const int* __restrict__ dst,
                                                int* __restrict__ cursor,
                                                int* __restrict__ csr)
{
    const int e = blockIdx.x * 256 + threadIdx.x;
    if (e >= GE) return;
    const int pos = atomicAdd(&cursor[dst[e]], 1);
    csr[pos] = src[e];
}

extern "C" void kernel_launch(void* const* d_in, const int* in_sizes, int n_in,
                              void* d_out, int out_size, void* d_ws, size_t ws_size,
                              hipStream_t stream)
{
    const float* x       = (const float*)d_in[0];
    const int*   src     = (const int*)d_in[1];            // edge_index[0]
    const int*   dst     = ((const int*)d_in[1]) + GE;     // edge_index[1]
    const float* W_in    = (const float*)d_in[2];
    const float* b_in    = (const float*)d_in[3];
    const float* W_convs = (const float*)d_in[4];          // [3,128,128]
    const float* b_convs = (const float*)d_in[5];          // [3,128]
    const float* W_out   = (const float*)d_in[6];          // [64,512]
    const float* b_out   = (const float*)d_in[7];
    float*       out     = (float*)d_out;                  // [GN,64]

    // d_ws: cat [GN,512] fp32 + pre-converted weight planes (hi/lo bf16)
    float*  cat = (float*)d_ws;
    __bf16* Whi = (__bf16*)(cat + (size_t)GN * 512);
    __bf16* Wlo = Whi + 98304;

    // CSR scratch in d_out (dead until final kernel overwrites it)
    int* deg       = (int*)d_out;
    int* row_start = deg + GN;
    int* cursor    = row_start + GN;
    int* blockSums = cursor + GN;
    int* blockOffs = blockSums + 128;
    int* csr       = blockOffs + 128;

    const dim3 blk(256);
    const dim3 gblk(512);
    const int edge_blocks  = (GE + 255) / 256;
    const int node_blocks  = (GN + 255) / 256;
    const int layer_blocks = (GN + 63) / 64;     // 1563
    const int final_blocks = (GN + 127) / 128;   // 782

    // --- CSR build (graph static; reused by all 3 layers) ---
    hipMemsetAsync(deg, 0, GN * sizeof(int), stream);
    count_deg<<<edge_blocks, blk, 0, stream>>>(dst, deg);
    scan_pass1<<<SCAN_NBLK, blk, 0, stream>>>(deg, row_start, blockSums);
    scan_pass2<<<1, 128, 0, stream>>>(blockSums, blockOffs, SCAN_NBLK);
    scan_pass3<<<node_blocks, blk, 0, stream>>>(row_start, blockOffs, cursor);
    fill_csr<<<edge_blocks, blk, 0, stream>>>(src, dst, cursor, csr);

    // --- weight pre-conversion (hi/lo bf16 planes) ---
    convert_w<<<(98304 + 255) / 256, blk, 0, stream>>>(W_in, W_convs, W_out, Whi, Wlo);

    // --- input projection -> cat block 0 ---
    gin_layer<false><<<layer_blocks, gblk, 0, stream>>>(
        x, 128, nullptr, nullptr, nullptr, Whi, Wlo, b_in, cat, 512);

    // --- three fused GIN layers (branchless pipelined gather + linear) ---
    for (int i = 0; i < 3; ++i) {
        gin_layer<true><<<layer_blocks, gblk, 0, stream>>>(
            cat + i * 128, 512, row_start, deg, csr,
            Whi + 16384 + i * 16384, Wlo + 16384 + i * 16384,
            b_convs + (size_t)i * 128, cat + (i + 1) * 128, 512);
    }

    // --- output projection + fused softmax -> d_out ---
    final_gemm_softmax<<<final_blocks, gblk, 0, stream>>>(
        cat, Whi + 65536, Wlo + 65536, b_out, out);
}

// Round 10
// 535.167 us; speedup vs baseline: 3.1078x; 1.1147x over previous
//
#include <hip/hip_runtime.h>
#include <hip/hip_bf16.h>
#include <hip/hip_fp16.h>

#define GN 100000
#define GE 600000
#define SCAN_NBLK 98   // ceil(GN / 1024)

typedef __bf16    bf16x8 __attribute__((ext_vector_type(8)));
typedef __bf16    bf16x4 __attribute__((ext_vector_type(4)));
typedef _Float16  f16x8  __attribute__((ext_vector_type(8)));
typedef float     f32x4  __attribute__((ext_vector_type(4)));

// ---------------------------------------------------------------------------
// Weight pre-conversion (layer weights only; W_out handled inline in final):
// [0,16384) = W_in[128,128]; [16384,65536) = W_convs[3][128][128].
// ---------------------------------------------------------------------------
__global__ __launch_bounds__(256) void convert_w(
    const float* __restrict__ Win, const float* __restrict__ Wc,
    __bf16* __restrict__ hi, __bf16* __restrict__ lo)
{
    const int i = blockIdx.x * 256 + threadIdx.x;
    if (i >= 65536) return;
    const float v = (i < 16384) ? Win[i] : Wc[i - 16384];
    const __bf16 h = (__bf16)v;
    hi[i] = h;
    lo[i] = (__bf16)(v - (float)h);
}

// ---------------------------------------------------------------------------
// Fused GIN layer: C[64-row tile, 128] = (gather(H) if GATHER else H) @ W^T + b
//
// r9 post-mortem: bf16 neighbor storage -> absmax 0.082 (4x over threshold);
// fp16 (2^-11 rel err, 8x better) predicted ~0.012. Structure unchanged:
// dense Hf[GN,128] fp16 copy (25.6MB, LLC-resident, 256B sequential rows —
// kills the 2KB-stride set-conflict thrashing behind r8's FETCH=166MB),
// half the gather bytes. Self term stays fp32 from cat.
// Phase B: in-register hi/lo split + 3-term MFMA. Phase C: coalesced stores
// of C (fp32) and HfOut (fp16).
// ---------------------------------------------------------------------------
template<bool GATHER>
__global__ __launch_bounds__(512, 4) void gin_layer(
    const float* __restrict__ H, int ldH,      // fp32 self rows (cat block / x)
    const _Float16* __restrict__ HfIn,         // dense fp16 copy for gather
    const int* __restrict__ row_start,
    const int* __restrict__ deg,
    const int* __restrict__ csr,
    const __bf16* __restrict__ Whi,            // [128,128]
    const __bf16* __restrict__ Wlo,
    const float* __restrict__ bias,            // [128]
    float* __restrict__ C, int ldC,
    _Float16* __restrict__ HfOut)              // dense fp16 copy of C (or null)
{
    constexpr int K   = 128;
    constexpr int ALD = 132;    // fp32 LDS ld: 128 + 4 -> 2-way-free banks, 16B aligned

    __shared__ float Acc[64 * ALD];      // 33792 B

    const int tid  = threadIdx.x;
    const int wave = tid >> 6;
    const int lane = tid & 63;
    const int row0 = blockIdx.x * 64;
    const int wm   = (wave >> 2) * 32;   // 0/32
    const int wn   = (wave & 3) * 32;    // 0/32/64/96
    const int quad = lane >> 4;
    const int l15  = lane & 15;

    // ---- Phase A1: Acc = self rows (fp32, coalesced) ----
#pragma unroll
    for (int p = 0; p < 4; ++p) {
        const int q  = tid + p * 512;     // float4 index in [0,2048)
        const int r  = q >> 5;            // 32 float4 per row
        const int c4 = (q & 31) * 4;
        float4 v = make_float4(0.f, 0.f, 0.f, 0.f);
        if (row0 + r < GN) v = *(const float4*)(H + (size_t)(row0 + r) * ldH + c4);
        *(float4*)&Acc[r * ALD + c4] = v;
    }

    // ---- Phase A2 (GATHER): branchless pipelined 8-row fp16 gather ----
    if (GATHER) {
        const uint* Hw = (const uint*)HfIn;   // 64 uints per row (2 fp16 each)
        float2 acc8[8];
        int start8[8], deg8[8];
        int maxd = 0;
#pragma unroll
        for (int r = 0; r < 8; ++r) {
            acc8[r] = make_float2(0.f, 0.f);
            const int v = row0 + wave * 8 + r;
            start8[r] = (v < GN) ? row_start[v] : 0;
            deg8[r]   = (v < GN) ? deg[v] : 0;
            maxd = max(maxd, deg8[r]);
        }

        int scur[8];
#pragma unroll
        for (int r = 0; r < 8; ++r) {
            const int s = csr[start8[r]];
            scur[r] = min(max(s, 0), GN - 1);
        }

        for (int k = 0; k < maxd; ++k) {
            int snext[8];
#pragma unroll
            for (int r = 0; r < 8; ++r) {
                const int kk = max(min(k + 1, deg8[r] - 1), 0);
                snext[r] = csr[start8[r] + kk];
            }
            uint t[8];
#pragma unroll
            for (int r = 0; r < 8; ++r)
                t[r] = Hw[(size_t)scur[r] * 64 + lane];
#pragma unroll
            for (int r = 0; r < 8; ++r) {
                const float m = (k < deg8[r]) ? 1.f : 0.f;
                union { uint u; _Float16 h[2]; } cv;
                cv.u = t[r];
                acc8[r].x = fmaf(m, (float)cv.h[0], acc8[r].x);
                acc8[r].y = fmaf(m, (float)cv.h[1], acc8[r].y);
                scur[r] = min(max(snext[r], 0), GN - 1);
            }
        }

        __syncthreads();   // A1 writes complete before owned RMW
        const int j = lane * 2;
#pragma unroll
        for (int r = 0; r < 8; ++r) {
            float* a = &Acc[(wave * 8 + r) * ALD + j];
            a[0] += acc8[r].x;
            a[1] += acc8[r].y;
        }
    }
    __syncthreads();

    // ---- Phase B: MFMA with in-register hi/lo split of A ----
    f32x4 acc[2][2];
#pragma unroll
    for (int i = 0; i < 2; ++i)
#pragma unroll
        for (int j = 0; j < 2; ++j) acc[i][j] = (f32x4)(0.0f);

#pragma unroll
    for (int ks = 0; ks < 4; ++ks) {
        const int kt = ks * 32 + quad * 8;
        bf16x8 ahi[2], alo[2];
#pragma unroll
        for (int mt = 0; mt < 2; ++mt) {
            const float* ap = &Acc[(wm + mt * 16 + l15) * ALD + kt];
            const f32x4 p = *(const f32x4*)ap;
            const f32x4 q = *(const f32x4*)(ap + 4);
#pragma unroll
            for (int e = 0; e < 4; ++e) {
                const __bf16 hp = (__bf16)p[e];
                const __bf16 hq = (__bf16)q[e];
                ahi[mt][e]     = hp;
                ahi[mt][e + 4] = hq;
                alo[mt][e]     = (__bf16)(p[e] - (float)hp);
                alo[mt][e + 4] = (__bf16)(q[e] - (float)hq);
            }
        }
        bf16x8 whi[2], wlo[2];
#pragma unroll
        for (int nt = 0; nt < 2; ++nt) {
            const int n = wn + nt * 16 + l15;
            whi[nt] = *(const bf16x8*)(Whi + (size_t)n * K + kt);
            wlo[nt] = *(const bf16x8*)(Wlo + (size_t)n * K + kt);
        }
#pragma unroll
        for (int mt = 0; mt < 2; ++mt)
#pragma unroll
            for (int nt = 0; nt < 2; ++nt) {
                acc[mt][nt] = __builtin_amdgcn_mfma_f32_16x16x32_bf16(
                    ahi[mt], whi[nt], acc[mt][nt], 0, 0, 0);
                acc[mt][nt] = __builtin_amdgcn_mfma_f32_16x16x32_bf16(
                    ahi[mt], wlo[nt], acc[mt][nt], 0, 0, 0);
                acc[mt][nt] = __builtin_amdgcn_mfma_f32_16x16x32_bf16(
                    alo[mt], whi[nt], acc[mt][nt], 0, 0, 0);
            }
    }
    __syncthreads();

    // ---- Phase C: epilogue via Acc (reused), coalesced fp32 + fp16 stores ----
#pragma unroll
    for (int nt = 0; nt < 2; ++nt) {
        const int col = wn + nt * 16 + l15;
        const float b = bias[col];
#pragma unroll
        for (int mt = 0; mt < 2; ++mt)
#pragma unroll
            for (int r4 = 0; r4 < 4; ++r4)
                Acc[(wm + mt * 16 + quad * 4 + r4) * ALD + col] = acc[mt][nt][r4] + b;
    }
    __syncthreads();
#pragma unroll
    for (int p = 0; p < 4; ++p) {
        const int q  = tid + p * 512;
        const int r  = q >> 5;           // 32 float4 per row
        const int c4 = (q & 31) * 4;
        const int gr = row0 + r;
        if (gr < GN)
            *(float4*)(C + (size_t)gr * ldC + c4) = *(const float4*)&Acc[r * ALD + c4];
    }
    if (HfOut) {
#pragma unroll
        for (int p = 0; p < 2; ++p) {
            const int q = tid + p * 512;  // fp16x8 group in [0,1024)
            const int r = q >> 4;         // 16 groups per row
            const int g = (q & 15) * 8;
            const int gr = row0 + r;
            if (gr < GN) {
                const float4 a = *(const float4*)&Acc[r * ALD + g];
                const float4 b = *(const float4*)&Acc[r * ALD + g + 4];
                f16x8 o = {(_Float16)a.x, (_Float16)a.y, (_Float16)a.z, (_Float16)a.w,
                           (_Float16)b.x, (_Float16)b.y, (_Float16)b.z, (_Float16)b.w};
                *(f16x8*)&HfOut[(size_t)gr * 128 + g] = o;
            }
        }
    }
}

// ---------------------------------------------------------------------------
// Final projection + fused softmax: out[GN,64] = softmax(cat @ W_out^T + b)
// BM=128, BN=64, K=512 in BK=64 chunks. W_out converted inline from fp32.
// ---------------------------------------------------------------------------
__global__ __launch_bounds__(512, 2) void final_gemm_softmax(
    const float* __restrict__ A,        // cat, ld 512
    const float* __restrict__ Wout,     // [64,512] fp32
    const float* __restrict__ bias,     // [64]
    float* __restrict__ out)            // [GN,64]
{
    constexpr int K   = 512;
    constexpr int ALD = 72;    // 64 + 8
    constexpr int CLD = 68;    // 64 + 4

    __shared__ char smem_raw[128 * ALD * 2 * 2];   // 36864 B
    __bf16* Ahi = (__bf16*)smem_raw;
    __bf16* Alo = Ahi + 128 * ALD;
    float*  Cst = (float*)smem_raw;                // 128*68*4 = 34816 B

    const int tid  = threadIdx.x;
    const int wave = tid >> 6;
    const int lane = tid & 63;
    const int row0 = blockIdx.x * 128;
    const int wm   = (wave >> 1) * 32;   // 0/32/64/96
    const int wn   = (wave & 1) * 32;    // 0/32
    const int quad = lane >> 4;
    const int l15  = lane & 15;

    f32x4 acc[2][2];
#pragma unroll
    for (int i = 0; i < 2; ++i)
#pragma unroll
        for (int j = 0; j < 2; ++j) acc[i][j] = (f32x4)(0.0f);

    for (int k0 = 0; k0 < K; k0 += 64) {
#pragma unroll
        for (int p = 0; p < 4; ++p) {
            const int q  = tid + p * 512;
            const int f  = q * 4;
            const int r  = f >> 6;       // 64 floats per row-chunk
            const int kc = f & 63;
            float4 v4 = make_float4(0.f, 0.f, 0.f, 0.f);
            const int gr = row0 + r;
            if (gr < GN) v4 = *(const float4*)(A + (size_t)gr * 512 + k0 + kc);
            const __bf16 h0 = (__bf16)v4.x, h1 = (__bf16)v4.y,
                         h2 = (__bf16)v4.z, h3 = (__bf16)v4.w;
            const int idx = r * ALD + kc;
            *(bf16x4*)&Ahi[idx] = (bf16x4){h0, h1, h2, h3};
            *(bf16x4*)&Alo[idx] = (bf16x4){(__bf16)(v4.x - (float)h0),
                                           (__bf16)(v4.y - (float)h1),
                                           (__bf16)(v4.z - (float)h2),
                                           (__bf16)(v4.w - (float)h3)};
        }
        __syncthreads();

#pragma unroll
        for (int ks = 0; ks < 2; ++ks) {
            const int kt = ks * 32 + quad * 8;
            bf16x8 ahi[2], alo[2];
#pragma unroll
            for (int mt = 0; mt < 2; ++mt) {
                const int idx = (wm + mt * 16 + l15) * ALD + kt;
                ahi[mt] = *(const bf16x8*)&Ahi[idx];
                alo[mt] = *(const bf16x8*)&Alo[idx];
            }
            bf16x8 whi[2], wlo[2];
#pragma unroll
            for (int nt = 0; nt < 2; ++nt) {
                const int n = wn + nt * 16 + l15;
                const float* wp = Wout + (size_t)n * K + k0 + kt;
                const float4 p = *(const float4*)wp;
                const float4 q = *(const float4*)(wp + 4);
                float pv[8] = {p.x, p.y, p.z, p.w, q.x, q.y, q.z, q.w};
#pragma unroll
                for (int e = 0; e < 8; ++e) {
                    const __bf16 h = (__bf16)pv[e];
                    whi[nt][e] = h;
                    wlo[nt][e] = (__bf16)(pv[e] - (float)h);
                }
            }
#pragma unroll
            for (int mt = 0; mt < 2; ++mt)
#pragma unroll
                for (int nt = 0; nt < 2; ++nt) {
                    acc[mt][nt] = __builtin_amdgcn_mfma_f32_16x16x32_bf16(
                        ahi[mt], whi[nt], acc[mt][nt], 0, 0, 0);
                    acc[mt][nt] = __builtin_amdgcn_mfma_f32_16x16x32_bf16(
                        ahi[mt], wlo[nt], acc[mt][nt], 0, 0, 0);
                    acc[mt][nt] = __builtin_amdgcn_mfma_f32_16x16x32_bf16(
                        alo[mt], whi[nt], acc[mt][nt], 0, 0, 0);
                }
        }
        __syncthreads();
    }

    // epilogue -> LDS, + bias
#pragma unroll
    for (int nt = 0; nt < 2; ++nt) {
        const int col = wn + nt * 16 + l15;
        const float b = bias[col];
#pragma unroll
        for (int mt = 0; mt < 2; ++mt)
#pragma unroll
            for (int r4 = 0; r4 < 4; ++r4)
                Cst[(wm + mt * 16 + quad * 4 + r4) * CLD + col] = acc[mt][nt][r4] + b;
    }
    __syncthreads();

    // fused softmax: one wave per row, 64 lanes = 64 cols
    for (int i = 0; i < 16; ++i) {
        const int r = wave * 16 + i;
        const float v = Cst[r * CLD + lane];
        float m = v;
#pragma unroll
        for (int off = 32; off > 0; off >>= 1) m = fmaxf(m, __shfl_xor(m, off));
        const float e = __expf(v - m);
        float s = e;
#pragma unroll
        for (int off = 32; off > 0; off >>= 1) s += __shfl_xor(s, off);
        const int gr = row0 + r;
        if (gr < GN) out[(size_t)gr * 64 + lane] = e / s;
    }
}

// ---------------------------------------------------------------------------
// CSR construction (graph static; built once per launch, used 3x)
// ---------------------------------------------------------------------------
__global__ __launch_bounds__(256) void count_deg(const int* __restrict__ dst,
                                                 int* __restrict__ deg)
{
    const int e = blockIdx.x * 256 + threadIdx.x;
    if (e < GE) atomicAdd(&deg[dst[e]], 1);
}

__global__ __launch_bounds__(256) void scan_pass1(const int* __restrict__ deg,
                                                  int* __restrict__ excl,
                                                  int* __restrict__ blockSums)
{
    __shared__ int s[256];
    const int t = threadIdx.x;
    const int base = blockIdx.x * 1024 + t * 4;

    int4 v = make_int4(0, 0, 0, 0);
    if (base + 3 < GN) {
        v = *(const int4*)(deg + base);
    } else {
        if (base + 0 < GN) v.x = deg[base + 0];
        if (base + 1 < GN) v.y = deg[base + 1];
        if (base + 2 < GN) v.z = deg[base + 2];
        if (base + 3 < GN) v.w = deg[base + 3];
    }
    const int mysum = v.x + v.y + v.z + v.w;
    s[t] = mysum;
    __syncthreads();
    for (int off = 1; off < 256; off <<= 1) {
        const int val = (t >= off) ? s[t - off] : 0;
        __syncthreads();
        s[t] += val;
        __syncthreads();
    }
    int4 o;
    o.x = s[t] - mysum;
    o.y = o.x + v.x;
    o.z = o.y + v.y;
    o.w = o.z + v.z;
    if (base + 3 < GN) {
        *(int4*)(excl + base) = o;
    } else {
        if (base + 0 < GN) excl[base + 0] = o.x;
        if (base + 1 < GN) excl[base + 1] = o.y;
        if (base + 2 < GN) excl[base + 2] = o.z;
        if (base + 3 < GN) excl[base + 3] = o.w;
    }
    if (t == 255) blockSums[blockIdx.x] = s[255];
}

__global__ __launch_bounds__(128) void scan_pass2(const int* __restrict__ blockSums,
                                                  int* __restrict__ blockOffs, int n)
{
    __shared__ int s[128];
    const int t = threadIdx.x;
    const int v = (t < n) ? blockSums[t] : 0;
    s[t] = v;
    __syncthreads();
    for (int off = 1; off < 128; off <<= 1) {
        const int val = (t >= off) ? s[t - off] : 0;
        __syncthreads();
        s[t] += val;
        __syncthreads();
    }
    if (t < n) blockOffs[t] = s[t] - v;
}

__global__ __launch_bounds__(256) void scan_pass3(int* __restrict__ excl,
                                                  const int* __restrict__ blockOffs,
                                                  int* __restrict__ cursor)
{
    const int i = blockIdx.x * 256 + threadIdx.x;
    if (i >= GN) return;
    const int v = excl[i] + blockOffs[i >> 10];
    excl[i]   = v;   // row_start
    cursor[i] = v;   // running cursor for fill
}

__global__ __launch_bounds__(256) void fill_csr(const int* __restrict__ src,
                                                const int* __restrict__ dst,
                                                int* __restrict__ cursor,
                                                int* __restrict__ csr)
{
    const int e = blockIdx.x * 256 + threadIdx.x;
    if (e >= GE) return;
    const int pos = atomicAdd(&cursor[dst[e]], 1);
    csr[pos] = src[e];
}

extern "C" void kernel_launch(void* const* d_in, const int* in_sizes, int n_in,
                              void* d_out, int out_size, void* d_ws, size_t ws_size,
                              hipStream_t stream)
{
    const float* x       = (const float*)d_in[0];
    const int*   src     = (const int*)d_in[1];            // edge_index[0]
    const int*   dst     = ((const int*)d_in[1]) + GE;     // edge_index[1]
    const float* W_in    = (const float*)d_in[2];
    const float* b_in    = (const float*)d_in[3];
    const float* W_convs = (const float*)d_in[4];          // [3,128,128]
    const float* b_convs = (const float*)d_in[5];          // [3,128]
    const float* W_out   = (const float*)d_in[6];          // [64,512]
    const float* b_out   = (const float*)d_in[7];
    float*       out     = (float*)d_out;                  // [GN,64]

    // d_ws: cat [GN,512] fp32 (204.8MB) + Hf ping-pong (2 x 25.6MB) = 256.0MB
    float*    cat = (float*)d_ws;
    _Float16* Hf0 = (_Float16*)((char*)d_ws + (size_t)GN * 512 * 4);
    _Float16* Hf1 = Hf0 + (size_t)GN * 128;

    // d_out: CSR scratch + layer-weight planes (dead until final kernel,
    // which reads none of this and overwrites it with the real output).
    int*    deg       = (int*)d_out;
    int*    row_start = deg + GN;
    int*    cursor    = row_start + GN;
    int*    blockSums = cursor + GN;
    int*    blockOffs = blockSums + 128;
    int*    csr       = blockOffs + 128;
    __bf16* Whi       = (__bf16*)(csr + GE);   // 65536 bf16
    __bf16* Wlo       = Whi + 65536;

    const dim3 blk(256);
    const dim3 gblk(512);
    const int edge_blocks  = (GE + 255) / 256;
    const int node_blocks  = (GN + 255) / 256;
    const int layer_blocks = (GN + 63) / 64;     // 1563
    const int final_blocks = (GN + 127) / 128;   // 782

    // --- CSR build (graph static; reused by all 3 layers) ---
    hipMemsetAsync(deg, 0, GN * sizeof(int), stream);
    count_deg<<<edge_blocks, blk, 0, stream>>>(dst, deg);
    scan_pass1<<<SCAN_NBLK, blk, 0, stream>>>(deg, row_start, blockSums);
    scan_pass2<<<1, 128, 0, stream>>>(blockSums, blockOffs, SCAN_NBLK);
    scan_pass3<<<node_blocks, blk, 0, stream>>>(row_start, blockOffs, cursor);
    fill_csr<<<edge_blocks, blk, 0, stream>>>(src, dst, cursor, csr);

    // --- layer-weight pre-conversion (hi/lo bf16 planes) ---
    convert_w<<<(65536 + 255) / 256, blk, 0, stream>>>(W_in, W_convs, Whi, Wlo);

    // --- input projection -> cat block 0 + Hf0 ---
    gin_layer<false><<<layer_blocks, gblk, 0, stream>>>(
        x, 128, nullptr, nullptr, nullptr, nullptr,
        Whi, Wlo, b_in, cat, 512, Hf0);

    // --- three fused GIN layers: fp16 gather (ping-pong Hf) + linear ---
    _Float16* hin[3]  = {Hf0, Hf1, Hf0};
    _Float16* hout[3] = {Hf1, Hf0, nullptr};
    for (int i = 0; i < 3; ++i) {
        gin_layer<true><<<layer_blocks, gblk, 0, stream>>>(
            cat + i * 128, 512, hin[i], row_start, deg, csr,
            Whi + 16384 + i * 16384, Wlo + 16384 + i * 16384,
            b_convs + (size_t)i * 128, cat + (i + 1) * 128, 512, hout[i]);
    }

    // --- output projection + fused softmax -> d_out ---
    final_gemm_softmax<<<final_blocks, gblk, 0, stream>>>(
        cat, W_out, b_out, out);
}

// Round 11
// 524.276 us; speedup vs baseline: 3.1724x; 1.0208x over previous
//
#include <hip/hip_runtime.h>
#include <hip/hip_bf16.h>
#include <hip/hip_fp16.h>

#define GN 100000
#define GE 600000
#define SCAN_NBLK 98   // ceil(GN / 1024)

typedef __bf16    bf16x8 __attribute__((ext_vector_type(8)));
typedef __bf16    bf16x4 __attribute__((ext_vector_type(4)));
typedef _Float16  f16x8  __attribute__((ext_vector_type(8)));
typedef float     f32x4  __attribute__((ext_vector_type(4)));

// ---------------------------------------------------------------------------
// Weight pre-conversion: fp32 -> (hi, lo) bf16 planes, ONCE per launch.
// [0,16384) W_in[128,128]; [16384,65536) W_convs[3][128][128];
// [65536,98304) W_out[64,512]. All row-major [OC, K].
// ---------------------------------------------------------------------------
__global__ __launch_bounds__(256) void convert_w(
    const float* __restrict__ Win, const float* __restrict__ Wc,
    const float* __restrict__ Wout,
    __bf16* __restrict__ hi, __bf16* __restrict__ lo)
{
    const int i = blockIdx.x * 256 + threadIdx.x;
    if (i >= 98304) return;
    float v;
    if (i < 16384)      v = Win[i];
    else if (i < 65536) v = Wc[i - 16384];
    else                v = Wout[i - 65536];
    const __bf16 h = (__bf16)v;
    hi[i] = h;
    lo[i] = (__bf16)(v - (float)h);
}

// ---------------------------------------------------------------------------
// Fused GIN layer (layers 0..2 of the pipeline): C = (gather?) @ W^T + b.
// cat buffer is now [GN,384] (blocks 0..2); layer 3 is fused into gin_final.
// Structure as r10 (branchless pipelined fp16 gather, in-register hi/lo split,
// 3-term MFMA, coalesced epilogue + fp16 mirror for next layer's gather).
// ---------------------------------------------------------------------------
template<bool GATHER>
__global__ __launch_bounds__(512, 4) void gin_layer(
    const float* __restrict__ H, int ldH,      // fp32 self rows (cat block / x)
    const _Float16* __restrict__ HfIn,         // dense fp16 copy for gather
    const int* __restrict__ row_start,
    const int* __restrict__ deg,
    const int* __restrict__ csr,
    const __bf16* __restrict__ Whi,            // [128,128]
    const __bf16* __restrict__ Wlo,
    const float* __restrict__ bias,            // [128]
    float* __restrict__ C, int ldC,
    _Float16* __restrict__ HfOut)              // dense fp16 copy of C
{
    constexpr int K   = 128;
    constexpr int ALD = 132;    // fp32 LDS ld: 128 + 4

    __shared__ float Acc[64 * ALD];      // 33792 B

    const int tid  = threadIdx.x;
    const int wave = tid >> 6;
    const int lane = tid & 63;
    const int row0 = blockIdx.x * 64;
    const int wm   = (wave >> 2) * 32;   // 0/32
    const int wn   = (wave & 3) * 32;    // 0/32/64/96
    const int quad = lane >> 4;
    const int l15  = lane & 15;

    // ---- Phase A1: Acc = self rows ----
#pragma unroll
    for (int p = 0; p < 4; ++p) {
        const int q  = tid + p * 512;
        const int r  = q >> 5;
        const int c4 = (q & 31) * 4;
        float4 v = make_float4(0.f, 0.f, 0.f, 0.f);
        if (row0 + r < GN) v = *(const float4*)(H + (size_t)(row0 + r) * ldH + c4);
        *(float4*)&Acc[r * ALD + c4] = v;
    }

    // ---- Phase A2 (GATHER): branchless pipelined 8-row fp16 gather ----
    if (GATHER) {
        const uint* Hw = (const uint*)HfIn;
        float2 acc8[8];
        int start8[8], deg8[8];
        int maxd = 0;
#pragma unroll
        for (int r = 0; r < 8; ++r) {
            acc8[r] = make_float2(0.f, 0.f);
            const int v = row0 + wave * 8 + r;
            start8[r] = (v < GN) ? row_start[v] : 0;
            deg8[r]   = (v < GN) ? deg[v] : 0;
            maxd = max(maxd, deg8[r]);
        }
        int scur[8];
#pragma unroll
        for (int r = 0; r < 8; ++r) {
            const int s = csr[start8[r]];
            scur[r] = min(max(s, 0), GN - 1);
        }
        for (int k = 0; k < maxd; ++k) {
            int snext[8];
#pragma unroll
            for (int r = 0; r < 8; ++r) {
                const int kk = max(min(k + 1, deg8[r] - 1), 0);
                snext[r] = csr[start8[r] + kk];
            }
            uint t[8];
#pragma unroll
            for (int r = 0; r < 8; ++r)
                t[r] = Hw[(size_t)scur[r] * 64 + lane];
#pragma unroll
            for (int r = 0; r < 8; ++r) {
                const float m = (k < deg8[r]) ? 1.f : 0.f;
                union { uint u; _Float16 h[2]; } cv;
                cv.u = t[r];
                acc8[r].x = fmaf(m, (float)cv.h[0], acc8[r].x);
                acc8[r].y = fmaf(m, (float)cv.h[1], acc8[r].y);
                scur[r] = min(max(snext[r], 0), GN - 1);
            }
        }
        __syncthreads();
        const int j = lane * 2;
#pragma unroll
        for (int r = 0; r < 8; ++r) {
            float* a = &Acc[(wave * 8 + r) * ALD + j];
            a[0] += acc8[r].x;
            a[1] += acc8[r].y;
        }
    }
    __syncthreads();

    // ---- Phase B: 3-term MFMA with in-register hi/lo split of A ----
    f32x4 acc[2][2];
#pragma unroll
    for (int i = 0; i < 2; ++i)
#pragma unroll
        for (int j = 0; j < 2; ++j) acc[i][j] = (f32x4)(0.0f);

#pragma unroll
    for (int ks = 0; ks < 4; ++ks) {
        const int kt = ks * 32 + quad * 8;
        bf16x8 ahi[2], alo[2];
#pragma unroll
        for (int mt = 0; mt < 2; ++mt) {
            const float* ap = &Acc[(wm + mt * 16 + l15) * ALD + kt];
            const f32x4 p = *(const f32x4*)ap;
            const f32x4 q = *(const f32x4*)(ap + 4);
#pragma unroll
            for (int e = 0; e < 4; ++e) {
                const __bf16 hp = (__bf16)p[e];
                const __bf16 hq = (__bf16)q[e];
                ahi[mt][e]     = hp;
                ahi[mt][e + 4] = hq;
                alo[mt][e]     = (__bf16)(p[e] - (float)hp);
                alo[mt][e + 4] = (__bf16)(q[e] - (float)hq);
            }
        }
        bf16x8 whi[2], wlo[2];
#pragma unroll
        for (int nt = 0; nt < 2; ++nt) {
            const int n = wn + nt * 16 + l15;
            whi[nt] = *(const bf16x8*)(Whi + (size_t)n * K + kt);
            wlo[nt] = *(const bf16x8*)(Wlo + (size_t)n * K + kt);
        }
#pragma unroll
        for (int mt = 0; mt < 2; ++mt)
#pragma unroll
            for (int nt = 0; nt < 2; ++nt) {
                acc[mt][nt] = __builtin_amdgcn_mfma_f32_16x16x32_bf16(
                    ahi[mt], whi[nt], acc[mt][nt], 0, 0, 0);
                acc[mt][nt] = __builtin_amdgcn_mfma_f32_16x16x32_bf16(
                    ahi[mt], wlo[nt], acc[mt][nt], 0, 0, 0);
                acc[mt][nt] = __builtin_amdgcn_mfma_f32_16x16x32_bf16(
                    alo[mt], whi[nt], acc[mt][nt], 0, 0, 0);
            }
    }
    __syncthreads();

    // ---- Phase C: epilogue via Acc, coalesced fp32 + fp16 stores ----
#pragma unroll
    for (int nt = 0; nt < 2; ++nt) {
        const int col = wn + nt * 16 + l15;
        const float b = bias[col];
#pragma unroll
        for (int mt = 0; mt < 2; ++mt)
#pragma unroll
            for (int r4 = 0; r4 < 4; ++r4)
                Acc[(wm + mt * 16 + quad * 4 + r4) * ALD + col] = acc[mt][nt][r4] + b;
    }
    __syncthreads();
#pragma unroll
    for (int p = 0; p < 4; ++p) {
        const int q  = tid + p * 512;
        const int r  = q >> 5;
        const int c4 = (q & 31) * 4;
        const int gr = row0 + r;
        if (gr < GN)
            *(float4*)(C + (size_t)gr * ldC + c4) = *(const float4*)&Acc[r * ALD + c4];
    }
#pragma unroll
    for (int p = 0; p < 2; ++p) {
        const int q = tid + p * 512;
        const int r = q >> 4;
        const int g = (q & 15) * 8;
        const int gr = row0 + r;
        if (gr < GN) {
            const float4 a = *(const float4*)&Acc[r * ALD + g];
            const float4 b = *(const float4*)&Acc[r * ALD + g + 4];
            f16x8 o = {(_Float16)a.x, (_Float16)a.y, (_Float16)a.z, (_Float16)a.w,
                       (_Float16)b.x, (_Float16)b.y, (_Float16)b.z, (_Float16)b.w};
            *(f16x8*)&HfOut[(size_t)gr * 128 + g] = o;
        }
    }
}

// ---------------------------------------------------------------------------
// Fused layer 3 + output projection + softmax.
// Phase A: gather h2 (self from cat3 block 2, neighbors from Hf fp16).
// Phase B1: h3 = A @ Wc3^T + b3  -> kept in LDS (Acc), never written to HBM.
// Phase B2: out = [cat0|cat1|cat2|h3] @ W_out^T + b_out.  K=512; cols 0..384
//   read as in-register hi/lo fragments straight from cat3 global (L2/LLC),
//   cols 384..512 from Acc LDS. 8 waves = 2m x 2n x 2k; k-halves reduced in
//   LDS. Phase C: softmax per row -> out. Removes the standalone final kernel
//   (114us), the 51.2MB h3 write + 51.2MB re-read, and per-block W_out
//   conversion (pre-converted planes).
// ---------------------------------------------------------------------------
__global__ __launch_bounds__(512, 4) void gin_final(
    const float* __restrict__ cat3,            // [GN,384]
    const _Float16* __restrict__ HfIn,         // h2 fp16
    const int* __restrict__ row_start,
    const int* __restrict__ deg,
    const int* __restrict__ csr,
    const __bf16* __restrict__ Whi3,           // Wc[2] planes [128,128]
    const __bf16* __restrict__ Wlo3,
    const float* __restrict__ b3,              // [128]
    const __bf16* __restrict__ WhiO,           // W_out planes [64,512]
    const __bf16* __restrict__ WloO,
    const float* __restrict__ bO,              // [64]
    float* __restrict__ out)                   // [GN,64]
{
    constexpr int ALD = 132;
    constexpr int CLD = 68;

    __shared__ float Acc[64 * ALD];      // 33792 B
    __shared__ float Cst[64 * CLD];      // 17408 B

    const int tid  = threadIdx.x;
    const int wave = tid >> 6;
    const int lane = tid & 63;
    const int row0 = blockIdx.x * 64;
    const int quad = lane >> 4;
    const int l15  = lane & 15;

    // ---- Phase A1: self rows = cat3 block 2 ----
#pragma unroll
    for (int p = 0; p < 4; ++p) {
        const int q  = tid + p * 512;
        const int r  = q >> 5;
        const int c4 = (q & 31) * 4;
        float4 v = make_float4(0.f, 0.f, 0.f, 0.f);
        if (row0 + r < GN)
            v = *(const float4*)(cat3 + (size_t)(row0 + r) * 384 + 256 + c4);
        *(float4*)&Acc[r * ALD + c4] = v;
    }

    // ---- Phase A2: gather (same as gin_layer) ----
    {
        const uint* Hw = (const uint*)HfIn;
        float2 acc8[8];
        int start8[8], deg8[8];
        int maxd = 0;
#pragma unroll
        for (int r = 0; r < 8; ++r) {
            acc8[r] = make_float2(0.f, 0.f);
            const int v = row0 + wave * 8 + r;
            start8[r] = (v < GN) ? row_start[v] : 0;
            deg8[r]   = (v < GN) ? deg[v] : 0;
            maxd = max(maxd, deg8[r]);
        }
        int scur[8];
#pragma unroll
        for (int r = 0; r < 8; ++r) {
            const int s = csr[start8[r]];
            scur[r] = min(max(s, 0), GN - 1);
        }
        for (int k = 0; k < maxd; ++k) {
            int snext[8];
#pragma unroll
            for (int r = 0; r < 8; ++r) {
                const int kk = max(min(k + 1, deg8[r] - 1), 0);
                snext[r] = csr[start8[r] + kk];
            }
            uint t[8];
#pragma unroll
            for (int r = 0; r < 8; ++r)
                t[r] = Hw[(size_t)scur[r] * 64 + lane];
#pragma unroll
            for (int r = 0; r < 8; ++r) {
                const float m = (k < deg8[r]) ? 1.f : 0.f;
                union { uint u; _Float16 h[2]; } cv;
                cv.u = t[r];
                acc8[r].x = fmaf(m, (float)cv.h[0], acc8[r].x);
                acc8[r].y = fmaf(m, (float)cv.h[1], acc8[r].y);
                scur[r] = min(max(snext[r], 0), GN - 1);
            }
        }
        __syncthreads();
        const int j = lane * 2;
#pragma unroll
        for (int r = 0; r < 8; ++r) {
            float* a = &Acc[(wave * 8 + r) * ALD + j];
            a[0] += acc8[r].x;
            a[1] += acc8[r].y;
        }
    }
    __syncthreads();

    // ---- Phase B1: GEMM1 (K=128) -> h3, 2m x 4n wave grid ----
    const int wm = (wave >> 2) * 32;
    const int wn = (wave & 3) * 32;
    f32x4 acc1[2][2];
#pragma unroll
    for (int i = 0; i < 2; ++i)
#pragma unroll
        for (int j = 0; j < 2; ++j) acc1[i][j] = (f32x4)(0.0f);

#pragma unroll
    for (int ks = 0; ks < 4; ++ks) {
        const int kt = ks * 32 + quad * 8;
        bf16x8 ahi[2], alo[2];
#pragma unroll
        for (int mt = 0; mt < 2; ++mt) {
            const float* ap = &Acc[(wm + mt * 16 + l15) * ALD + kt];
            const f32x4 p = *(const f32x4*)ap;
            const f32x4 q = *(const f32x4*)(ap + 4);
#pragma unroll
            for (int e = 0; e < 4; ++e) {
                const __bf16 hp = (__bf16)p[e];
                const __bf16 hq = (__bf16)q[e];
                ahi[mt][e]     = hp;
                ahi[mt][e + 4] = hq;
                alo[mt][e]     = (__bf16)(p[e] - (float)hp);
                alo[mt][e + 4] = (__bf16)(q[e] - (float)hq);
            }
        }
        bf16x8 whi[2], wlo[2];
#pragma unroll
        for (int nt = 0; nt < 2; ++nt) {
            const int n = wn + nt * 16 + l15;
            whi[nt] = *(const bf16x8*)(Whi3 + (size_t)n * 128 + kt);
            wlo[nt] = *(const bf16x8*)(Wlo3 + (size_t)n * 128 + kt);
        }
#pragma unroll
        for (int mt = 0; mt < 2; ++mt)
#pragma unroll
            for (int nt = 0; nt < 2; ++nt) {
                acc1[mt][nt] = __builtin_amdgcn_mfma_f32_16x16x32_bf16(
                    ahi[mt], whi[nt], acc1[mt][nt], 0, 0, 0);
                acc1[mt][nt] = __builtin_amdgcn_mfma_f32_16x16x32_bf16(
                    ahi[mt], wlo[nt], acc1[mt][nt], 0, 0, 0);
                acc1[mt][nt] = __builtin_amdgcn_mfma_f32_16x16x32_bf16(
                    alo[mt], whi[nt], acc1[mt][nt], 0, 0, 0);
            }
    }
    __syncthreads();

    // h3 + b3 -> Acc (overwrites gather input; all reads done)
#pragma unroll
    for (int nt = 0; nt < 2; ++nt) {
        const int col = wn + nt * 16 + l15;
        const float b = b3[col];
#pragma unroll
        for (int mt = 0; mt < 2; ++mt)
#pragma unroll
            for (int r4 = 0; r4 < 4; ++r4)
                Acc[(wm + mt * 16 + quad * 4 + r4) * ALD + col] = acc1[mt][nt][r4] + b;
    }
    __syncthreads();

    // ---- Phase B2: GEMM2 (K=512), 2m x 2n x 2k wave grid ----
    const int wk  = wave & 1;
    const int wn2 = ((wave >> 1) & 1) * 32;
    const int wm2 = ((wave >> 2) & 1) * 32;
    f32x4 acc2[2][2];
#pragma unroll
    for (int i = 0; i < 2; ++i)
#pragma unroll
        for (int j = 0; j < 2; ++j) acc2[i][j] = (f32x4)(0.0f);

#pragma unroll
    for (int ks = 0; ks < 8; ++ks) {
        const int kg = wk * 256 + ks * 32 + quad * 8;
        bf16x8 ahi[2], alo[2];
#pragma unroll
        for (int mt = 0; mt < 2; ++mt) {
            const int row = wm2 + mt * 16 + l15;
            f32x4 p, q;
            if (kg < 384) {
                // direct global fragment (rows past GN read safe in-ws bytes;
                // their outputs are never stored)
                const float* ap = cat3 + (size_t)(row0 + row) * 384 + kg;
                p = *(const f32x4*)ap;
                q = *(const f32x4*)(ap + 4);
            } else {
                const float* ap = &Acc[row * ALD + (kg - 384)];
                p = *(const f32x4*)ap;
                q = *(const f32x4*)(ap + 4);
            }
#pragma unroll
            for (int e = 0; e < 4; ++e) {
                const __bf16 hp = (__bf16)p[e];
                const __bf16 hq = (__bf16)q[e];
                ahi[mt][e]     = hp;
                ahi[mt][e + 4] = hq;
                alo[mt][e]     = (__bf16)(p[e] - (float)hp);
                alo[mt][e + 4] = (__bf16)(q[e] - (float)hq);
            }
        }
        bf16x8 whi[2], wlo[2];
#pragma unroll
        for (int nt = 0; nt < 2; ++nt) {
            const int n = wn2 + nt * 16 + l15;
            whi[nt] = *(const bf16x8*)(WhiO + (size_t)n * 512 + kg);
            wlo[nt] = *(const bf16x8*)(WloO + (size_t)n * 512 + kg);
        }
#pragma unroll
        for (int mt = 0; mt < 2; ++mt)
#pragma unroll
            for (int nt = 0; nt < 2; ++nt) {
                acc2[mt][nt] = __builtin_amdgcn_mfma_f32_16x16x32_bf16(
                    ahi[mt], whi[nt], acc2[mt][nt], 0, 0, 0);
                acc2[mt][nt] = __builtin_amdgcn_mfma_f32_16x16x32_bf16(
                    ahi[mt], wlo[nt], acc2[mt][nt], 0, 0, 0);
                acc2[mt][nt] = __builtin_amdgcn_mfma_f32_16x16x32_bf16(
                    alo[mt], whi[nt], acc2[mt][nt], 0, 0, 0);
            }
    }

    // ---- k-half reduction in Cst ----
    if (wk == 1) {
#pragma unroll
        for (int nt = 0; nt < 2; ++nt)
#pragma unroll
            for (int mt = 0; mt < 2; ++mt)
#pragma unroll
                for (int r4 = 0; r4 < 4; ++r4)
                    Cst[(wm2 + mt * 16 + quad * 4 + r4) * CLD + wn2 + nt * 16 + l15]
                        = acc2[mt][nt][r4];
    }
    __syncthreads();
    if (wk == 0) {
#pragma unroll
        for (int nt = 0; nt < 2; ++nt) {
            const int col = wn2 + nt * 16 + l15;
            const float b = bO[col];
#pragma unroll
            for (int mt = 0; mt < 2; ++mt)
#pragma unroll
                for (int r4 = 0; r4 < 4; ++r4) {
                    const int idx = (wm2 + mt * 16 + quad * 4 + r4) * CLD + col;
                    Cst[idx] = Cst[idx] + acc2[mt][nt][r4] + b;
                }
        }
    }
    __syncthreads();

    // ---- Phase C: softmax, one wave per row (8 rows/wave) ----
    for (int i = 0; i < 8; ++i) {
        const int r = wave * 8 + i;
        const float v = Cst[r * CLD + lane];
        float m = v;
#pragma unroll
        for (int off = 32; off > 0; off >>= 1) m = fmaxf(m, __shfl_xor(m, off));
        const float e = __expf(v - m);
        float s = e;
#pragma unroll
        for (int off = 32; off > 0; off >>= 1) s += __shfl_xor(s, off);
        const int gr = row0 + r;
        if (gr < GN) out[(size_t)gr * 64 + lane] = e / s;
    }
}

// ---------------------------------------------------------------------------
// CSR construction (graph static; built once per launch)
// ---------------------------------------------------------------------------
__global__ __launch_bounds__(256) void count_deg(const int* __restrict__ dst,
                                                 int* __restrict__ deg)
{
    const int e = blockIdx.x * 256 + threadIdx.x;
    if (e < GE) atomicAdd(&deg[dst[e]], 1);
}

__global__ __launch_bounds__(256) void scan_pass1(const int* __restrict__ deg,
                                                  int* __restrict__ excl,
                                                  int* __restrict__ blockSums)
{
    __shared__ int s[256];
    const int t = threadIdx.x;
    const int base = blockIdx.x * 1024 + t * 4;

    int4 v = make_int4(0, 0, 0, 0);
    if (base + 3 < GN) {
        v = *(const int4*)(deg + base);
    } else {
        if (base + 0 < GN) v.x = deg[base + 0];
        if (base + 1 < GN) v.y = deg[base + 1];
        if (base + 2 < GN) v.z = deg[base + 2];
        if (base + 3 < GN) v.w = deg[base + 3];
    }
    const int mysum = v.x + v.y + v.z + v.w;
    s[t] = mysum;
    __syncthreads();
    for (int off = 1; off < 256; off <<= 1) {
        const int val = (t >= off) ? s[t - off] : 0;
        __syncthreads();
        s[t] += val;
        __syncthreads();
    }
    int4 o;
    o.x = s[t] - mysum;
    o.y = o.x + v.x;
    o.z = o.y + v.y;
    o.w = o.z + v.z;
    if (base + 3 < GN) {
        *(int4*)(excl + base) = o;
    } else {
        if (base + 0 < GN) excl[base + 0] = o.x;
        if (base + 1 < GN) excl[base + 1] = o.y;
        if (base + 2 < GN) excl[base + 2] = o.z;
        if (base + 3 < GN) excl[base + 3] = o.w;
    }
    if (t == 255) blockSums[blockIdx.x] = s[255];
}

__global__ __launch_bounds__(128) void scan_pass2(const int* __restrict__ blockSums,
                                                  int* __restrict__ blockOffs, int n)
{
    __shared__ int s[128];
    const int t = threadIdx.x;
    const int v = (t < n) ? blockSums[t] : 0;
    s[t] = v;
    __syncthreads();
    for (int off = 1; off < 128; off <<= 1) {
        const int val = (t >= off) ? s[t - off] : 0;
        __syncthreads();
        s[t] += val;
        __syncthreads();
    }
    if (t < n) blockOffs[t] = s[t] - v;
}

__global__ __launch_bounds__(256) void scan_pass3(int* __restrict__ excl,
                                                  const int* __restrict__ blockOffs,
                                                  int* __restrict__ cursor)
{
    const int i = blockIdx.x * 256 + threadIdx.x;
    if (i >= GN) return;
    const int v = excl[i] + blockOffs[i >> 10];
    excl[i]   = v;
    cursor[i] = v;
}

__global__ __launch_bounds__(256) void fill_csr(const int* __restrict__ src,
                                                const int* __restrict__ dst,
                                                int* __restrict__ cursor,
                                                int* __restrict__ csr)
{
    const int e = blockIdx.x * 256 + threadIdx.x;
    if (e >= GE) return;
    const int pos = atomicAdd(&cursor[dst[e]], 1);
    csr[pos] = src[e];
}

extern "C" void kernel_launch(void* const* d_in, const int* in_sizes, int n_in,
                              void* d_out, int out_size, void* d_ws, size_t ws_size,
                              hipStream_t stream)
{
    const float* x       = (const float*)d_in[0];
    const int*   src     = (const int*)d_in[1];            // edge_index[0]
    const int*   dst     = ((const int*)d_in[1]) + GE;     // edge_index[1]
    const float* W_in    = (const float*)d_in[2];
    const float* b_in    = (const float*)d_in[3];
    const float* W_convs = (const float*)d_in[4];          // [3,128,128]
    const float* b_convs = (const float*)d_in[5];          // [3,128]
    const float* W_out   = (const float*)d_in[6];          // [64,512]
    const float* b_out   = (const float*)d_in[7];
    float*       out     = (float*)d_out;                  // [GN,64]

    // d_ws layout (~209 MB of the >=256 MB workspace):
    //   cat3 [GN,384] fp32 | Hf0 | Hf1 (fp16 [GN,128] each) | CSR scratch |
    //   hi/lo weight planes (98304 bf16 each).  d_out holds ONLY the output.
    float*    cat3 = (float*)d_ws;
    _Float16* Hf0  = (_Float16*)(cat3 + (size_t)GN * 384);
    _Float16* Hf1  = Hf0 + (size_t)GN * 128;
    int*      deg       = (int*)(Hf1 + (size_t)GN * 128);
    int*      row_start = deg + GN;
    int*      cursor    = row_start + GN;
    int*      blockSums = cursor + GN;
    int*      blockOffs = blockSums + 128;
    int*      csr       = blockOffs + 128;
    __bf16*   Whi       = (__bf16*)(csr + GE);   // 98304 bf16
    __bf16*   Wlo       = Whi + 98304;

    const dim3 blk(256);
    const dim3 gblk(512);
    const int edge_blocks  = (GE + 255) / 256;
    const int node_blocks  = (GN + 255) / 256;
    const int layer_blocks = (GN + 63) / 64;     // 1563

    // --- CSR build ---
    hipMemsetAsync(deg, 0, GN * sizeof(int), stream);
    count_deg<<<edge_blocks, blk, 0, stream>>>(dst, deg);
    scan_pass1<<<SCAN_NBLK, blk, 0, stream>>>(deg, row_start, blockSums);
    scan_pass2<<<1, 128, 0, stream>>>(blockSums, blockOffs, SCAN_NBLK);
    scan_pass3<<<node_blocks, blk, 0, stream>>>(row_start, blockOffs, cursor);
    fill_csr<<<edge_blocks, blk, 0, stream>>>(src, dst, cursor, csr);

    // --- weight pre-conversion (all hi/lo planes incl. W_out) ---
    convert_w<<<(98304 + 255) / 256, blk, 0, stream>>>(W_in, W_convs, W_out, Whi, Wlo);

    // --- input projection -> cat3 block 0 + Hf0 ---
    gin_layer<false><<<layer_blocks, gblk, 0, stream>>>(
        x, 128, nullptr, nullptr, nullptr, nullptr,
        Whi, Wlo, b_in, cat3, 384, Hf0);

    // --- layers 1..2: fp16 gather (ping-pong Hf) + linear ---
    gin_layer<true><<<layer_blocks, gblk, 0, stream>>>(
        cat3, 384, Hf0, row_start, deg, csr,
        Whi + 16384, Wlo + 16384, b_convs, cat3 + 128, 384, Hf1);
    gin_layer<true><<<layer_blocks, gblk, 0, stream>>>(
        cat3 + 128, 384, Hf1, row_start, deg, csr,
        Whi + 32768, Wlo + 32768, b_convs + 128, cat3 + 256, 384, Hf0);

    // --- fused layer 3 + output projection + softmax -> d_out ---
    gin_final<<<layer_blocks, gblk, 0, stream>>>(
        cat3, Hf0, row_start, deg, csr,
        Whi + 49152, Wlo + 49152, b_convs + 256,
        Whi + 65536, Wlo + 65536, b_out, out);
}